// Round 5
// baseline (790.332 us; speedup 1.0000x reference)
//
#include <hip/hip_runtime.h>
#include <cstdint>

// SelfAttention fused pipeline, bf16 MFMA path.
// B=2 S=2048 DIM=4096 HQ=32 HKV=8 D=128, causal, start_pos=0.
//
// R7 = R6 held byte-identical (5th round without a successful bench; stack
// audited twice, decision tree pre-committed).
//  - gemm_bt8 (R3): 8-phase 256^2 BK=64 (T2 swizzle + T3/T4 counted vmcnt +
//    T5 setprio), 512 thr / 8 waves, 128 KB LDS, stage stream 7 quarters
//    ahead, vmcnt(6) per tile (vmcnt(0) last tile only).
//  - flash_attn (R5): K/V LDS double-buffered, ONE vmcnt(0)+barrier per
//    k-tile (stage kt+1 before compute of kt). Ps stride 64 + chunk-XOR,
//    LDS exactly 80 KB -> 2 blocks/CU. setprio around QK^T / PV clusters.
//
// ws layout (bytes):
//   xb    @ 0         : bf16[4096][4096]   x cast               (33.5 MB)
//   wt    @ 33554432  : bf16[6144][4096]   [wq^T*scale; wk^T; wv^T] (50.3 MB)
//   wot   @ 83886080  : bf16[4096][4096]   wo^T                 (33.5 MB)
//   qkv   @ 117440512 : bf16[4096][6144]   x@[wq wk wv]         (50.3 MB)
//   vt    @ 167772160 : bf16[2][8][128][2048] V^T per kv head   (8.4 MB)
//   ao    @ 176160768 : bf16[4096][4096]   attention output     (33.5 MB)
// total 209715200 bytes.

typedef __bf16 bf16;
typedef __bf16 bf16x8 __attribute__((ext_vector_type(8)));
typedef float f32x4 __attribute__((ext_vector_type(4)));

#define DEV_INLINE __device__ __forceinline__

DEV_INLINE void load_lds16(const bf16* g, bf16* l) {
  // async global->LDS, 16B per lane; LDS dest = wave-uniform base + lane*16
  __builtin_amdgcn_global_load_lds(
      (const __attribute__((address_space(1))) void*)g,
      (__attribute__((address_space(3))) void*)l, 16, 0, 0);
}

// ---------------- elementwise cast f32 -> bf16, 8 elems/thread ----------------
__global__ __launch_bounds__(256) void cast_f32_bf16(const float* __restrict__ in,
                                                     bf16* __restrict__ out, int n) {
  int i = (blockIdx.x * 256 + threadIdx.x) * 8;
  if (i >= n) return;
  float4 a = *(const float4*)(in + i);
  float4 b = *(const float4*)(in + i + 4);
  bf16x8 o;
  o[0] = (bf16)a.x; o[1] = (bf16)a.y; o[2] = (bf16)a.z; o[3] = (bf16)a.w;
  o[4] = (bf16)b.x; o[5] = (bf16)b.y; o[6] = (bf16)b.z; o[7] = (bf16)b.w;
  *(bf16x8*)(out + i) = o;
}

// --- merged transpose+cast of all 4 weights: f32 [K=4096][N] -> bf16 [N][4096]
__global__ __launch_bounds__(256) void transpose_cast_all(
    const float* __restrict__ wq, const float* __restrict__ wk,
    const float* __restrict__ wv, const float* __restrict__ wo,
    bf16* __restrict__ wt, bf16* __restrict__ wot, float qscale) {
  __shared__ float t[32][33];
  int bx = blockIdx.x, k0 = blockIdx.y * 32;
  const float* src;
  bf16* dst;
  int N, ncol0, nrow0;
  float scale = 1.0f;
  if (bx < 128) {        // wq -> wt rows [0,4096)
    src = wq; dst = wt; N = 4096; ncol0 = bx * 32; nrow0 = ncol0; scale = qscale;
  } else if (bx < 160) { // wk -> wt rows [4096,5120)
    src = wk; dst = wt; N = 1024; ncol0 = (bx - 128) * 32; nrow0 = 4096 + ncol0;
  } else if (bx < 192) { // wv -> wt rows [5120,6144)
    src = wv; dst = wt; N = 1024; ncol0 = (bx - 160) * 32; nrow0 = 5120 + ncol0;
  } else {               // wo -> wot
    src = wo; dst = wot; N = 4096; ncol0 = (bx - 192) * 32; nrow0 = ncol0;
  }
  int tx = threadIdx.x, ty = threadIdx.y;
#pragma unroll
  for (int i = 0; i < 32; i += 8)
    t[ty + i][tx] = src[(size_t)(k0 + ty + i) * N + ncol0 + tx];
  __syncthreads();
#pragma unroll
  for (int i = 0; i < 32; i += 8)
    dst[(size_t)(nrow0 + ty + i) * 4096 + k0 + tx] = (bf16)(t[tx][ty + i] * scale);
}

// ------ transpose V slice of qkv[4096][6144] -> vt[(b*8+h)*128 + d][2048] -----
__global__ __launch_bounds__(256) void transpose_v(const bf16* __restrict__ qkv,
                                                   bf16* __restrict__ vt) {
  __shared__ bf16 t[32][33];
  int s0 = blockIdx.x * 32, d0 = blockIdx.y * 32, bh = blockIdx.z;
  int b = bh >> 3, h = bh & 7;
  int tx = threadIdx.x, ty = threadIdx.y;
#pragma unroll
  for (int i = 0; i < 32; i += 8)
    t[ty + i][tx] =
        qkv[(size_t)(b * 2048 + s0 + ty + i) * 6144 + 5120 + h * 128 + d0 + tx];
  __syncthreads();
#pragma unroll
  for (int i = 0; i < 32; i += 8)
    vt[((size_t)bh * 128 + d0 + ty + i) * 2048 + s0 + tx] = t[tx][ty + i];
}

// ------------- 8-phase 256^2 GEMM: C[M][N] = A[M][K] * Bt[N][K]^T -------------
// 512 threads, waves (rm=w>>2 in 2, cn=w&3 in 4); per-wave C = 128x64
// (mi 0..7 x ni 0..3 fragments of 16x16). BK=64 (2 k-slices of 32).
// LDS quarters per dbuf (16 KB each, [128 idx][64 K] bf16, XOR-swizzled
// chunk' = chunk ^ (idx&7) within each 128B row):
//   Q0: A rows with (r>>6)&1==0; Q1: B cols h0; Q2: B cols h1; Q3: A rows h1
// Phase p computes C-quadrant, reads quarters, stages stream h=4T+p+7:
//   p0: read Q0+Q1 (12 dsr)  MFMA mi0-3 x ni0-1  stage Q3 of T+1
//   p1: read Q2    ( 4 dsr)  MFMA mi0-3 x ni2-3  stage Q0 of T+2
//   p2: read Q3    ( 8 dsr)  MFMA mi4-7 x ni0-1  stage Q1 of T+2
//   p3: (regs)     ( 0 dsr)  MFMA mi4-7 x ni2-3  stage Q2 of T+2
// Every quarter's last LDS read is >=1 barrier before its overwriting issue.
// vmcnt(6) (=3 quarters in flight) at each tile top; vmcnt(0) at last tile.
template <typename OT>
__global__ __launch_bounds__(512, 2) void gemm_bt8(const bf16* __restrict__ A,
                                                   const bf16* __restrict__ Bt,
                                                   OT* __restrict__ C,
                                                   int M, int N, int K) {
  __shared__ __align__(16) bf16 lds[2][4][128 * 64];
  const int t = threadIdx.x, w = t >> 6, l = t & 63;
  const int lr = l & 15, lh = l >> 4;
  const int rm = w >> 2, cn = w & 3;
  const int mBase = blockIdx.y * 256, nBase = blockIdx.x * 256;
  const int NT = K >> 6;

  // per-thread DMA source offsets (elements) for the two 512-chunk passes
  size_t gA0[2], gB0[2];
#pragma unroll
  for (int it = 0; it < 2; it++) {
    int c = it * 512 + t;            // 16B chunk id in [0,1024)
    int idx = c >> 3;                // LDS row within quarter
    int kc = (c & 7) ^ (idx & 7);    // logical K-chunk (8 els) stored here
    gA0[it] = (size_t)(mBase + (idx >> 6) * 128 + (idx & 63)) * K + kc * 8;
    gB0[it] = (size_t)(nBase + (idx >> 5) * 64 + (idx & 31)) * K + kc * 8;
  }
  const size_t strideA1 = (size_t)64 * K;   // +64 rows  (mih1)
  const size_t strideB1 = (size_t)32 * K;   // +32 cols  (nih1)
  const int ldst0 = (w * 64) * 8, ldst1 = (512 + w * 64) * 8;  // element offs

#define STAGE_Q(tile, q, base, off0, off1)                                  \
  do {                                                                      \
    int th_ = (tile);                                                       \
    if (th_ < NT) {                                                         \
      bf16* qb_ = &lds[th_ & 1][q][0];                                      \
      size_t ka_ = (size_t)th_ * 64;                                        \
      load_lds16((base) + (off0) + ka_, qb_ + ldst0);                       \
      load_lds16((base) + (off1) + ka_, qb_ + ldst1);                       \
    }                                                                       \
  } while (0)
#define STAGE_A0(tile) STAGE_Q(tile, 0, A, gA0[0], gA0[1])
#define STAGE_B0(tile) STAGE_Q(tile, 1, Bt, gB0[0], gB0[1])
#define STAGE_B1(tile) STAGE_Q(tile, 2, Bt, gB0[0] + strideB1, gB0[1] + strideB1)
#define STAGE_A1(tile) STAGE_Q(tile, 3, A, gA0[0] + strideA1, gA0[1] + strideA1)

  // prologue: stream h=0..6  (tile0 Q0,Q1,Q2,Q3; tile1 Q0,Q1,Q2)
  STAGE_A0(0); STAGE_B0(0); STAGE_B1(0); STAGE_A1(0);
  STAGE_A0(1); STAGE_B0(1); STAGE_B1(1);

  f32x4 acc[8][4] = {};
  bf16x8 aF[4][2], bF[4][2];
  // read-side addressing: idx&7 == lr&7 for all fragment reads
  const int rowA = (rm * 64 + lr) * 64;               // element off, mi=0
  const int colB = (cn * 32 + lr) * 64;               // element off, ni even
  const int xo0 = ((lh ^ (lr & 7)) << 3);             // ks=0 swizzled K-off
  const int xo1 = (((4 + lh) ^ (lr & 7)) << 3);       // ks=1

  for (int T = 0; T < NT; T++) {
    if (T < NT - 1) asm volatile("s_waitcnt vmcnt(6)" ::: "memory");
    else            asm volatile("s_waitcnt vmcnt(0)" ::: "memory");
    __builtin_amdgcn_s_barrier();
    const bf16* q0 = &lds[T & 1][0][0];
    const bf16* q1 = &lds[T & 1][1][0];
    const bf16* q2 = &lds[T & 1][2][0];
    const bf16* q3 = &lds[T & 1][3][0];

    // ---- phase 0: A-mih0 + B-nih0 reads; MFMA (mi0-3, ni0-1)
#pragma unroll
    for (int mi = 0; mi < 4; mi++) {
      aF[mi][0] = *(const bf16x8*)(q0 + rowA + mi * 1024 + xo0);
      aF[mi][1] = *(const bf16x8*)(q0 + rowA + mi * 1024 + xo1);
    }
#pragma unroll
    for (int ni = 0; ni < 2; ni++) {
      bF[ni][0] = *(const bf16x8*)(q1 + colB + ni * 1024 + xo0);
      bF[ni][1] = *(const bf16x8*)(q1 + colB + ni * 1024 + xo1);
    }
    STAGE_A1(T + 1);
    asm volatile("s_waitcnt lgkmcnt(8)" ::: "memory");
    __builtin_amdgcn_s_barrier();
    asm volatile("s_waitcnt lgkmcnt(0)" ::: "memory");
    __builtin_amdgcn_sched_barrier(0);
    __builtin_amdgcn_s_setprio(1);
#pragma unroll
    for (int mi = 0; mi < 4; mi++)
#pragma unroll
      for (int ni = 0; ni < 2; ni++) {
        acc[mi][ni] = __builtin_amdgcn_mfma_f32_16x16x32_bf16(aF[mi][0], bF[ni][0], acc[mi][ni], 0, 0, 0);
        acc[mi][ni] = __builtin_amdgcn_mfma_f32_16x16x32_bf16(aF[mi][1], bF[ni][1], acc[mi][ni], 0, 0, 0);
      }
    __builtin_amdgcn_s_setprio(0);
    __builtin_amdgcn_s_barrier();

    // ---- phase 1: B-nih1 reads; MFMA (mi0-3, ni2-3)
#pragma unroll
    for (int ni = 0; ni < 2; ni++) {
      bF[2 + ni][0] = *(const bf16x8*)(q2 + colB + ni * 1024 + xo0);
      bF[2 + ni][1] = *(const bf16x8*)(q2 + colB + ni * 1024 + xo1);
    }
    STAGE_A0(T + 2);
    __builtin_amdgcn_s_barrier();
    asm volatile("s_waitcnt lgkmcnt(0)" ::: "memory");
    __builtin_amdgcn_sched_barrier(0);
    __builtin_amdgcn_s_setprio(1);
#pragma unroll
    for (int mi = 0; mi < 4; mi++)
#pragma unroll
      for (int ni = 2; ni < 4; ni++) {
        acc[mi][ni] = __builtin_amdgcn_mfma_f32_16x16x32_bf16(aF[mi][0], bF[ni][0], acc[mi][ni], 0, 0, 0);
        acc[mi][ni] = __builtin_amdgcn_mfma_f32_16x16x32_bf16(aF[mi][1], bF[ni][1], acc[mi][ni], 0, 0, 0);
      }
    __builtin_amdgcn_s_setprio(0);
    __builtin_amdgcn_s_barrier();

    // ---- phase 2: A-mih1 reads (reuse aF); MFMA (mi4-7, ni0-1)
#pragma unroll
    for (int mi = 0; mi < 4; mi++) {
      aF[mi][0] = *(const bf16x8*)(q3 + rowA + mi * 1024 + xo0);
      aF[mi][1] = *(const bf16x8*)(q3 + rowA + mi * 1024 + xo1);
    }
    STAGE_B0(T + 2);
    __builtin_amdgcn_s_barrier();
    asm volatile("s_waitcnt lgkmcnt(0)" ::: "memory");
    __builtin_amdgcn_sched_barrier(0);
    __builtin_amdgcn_s_setprio(1);
#pragma unroll
    for (int mi = 0; mi < 4; mi++)
#pragma unroll
      for (int ni = 0; ni < 2; ni++) {
        acc[4 + mi][ni] = __builtin_amdgcn_mfma_f32_16x16x32_bf16(aF[mi][0], bF[ni][0], acc[4 + mi][ni], 0, 0, 0);
        acc[4 + mi][ni] = __builtin_amdgcn_mfma_f32_16x16x32_bf16(aF[mi][1], bF[ni][1], acc[4 + mi][ni], 0, 0, 0);
      }
    __builtin_amdgcn_s_setprio(0);
    __builtin_amdgcn_s_barrier();

    // ---- phase 3: register-only; MFMA (mi4-7, ni2-3)
    STAGE_B1(T + 2);
    __builtin_amdgcn_s_barrier();
    __builtin_amdgcn_s_setprio(1);
#pragma unroll
    for (int mi = 0; mi < 4; mi++)
#pragma unroll
      for (int ni = 2; ni < 4; ni++) {
        acc[4 + mi][ni] = __builtin_amdgcn_mfma_f32_16x16x32_bf16(aF[mi][0], bF[ni][0], acc[4 + mi][ni], 0, 0, 0);
        acc[4 + mi][ni] = __builtin_amdgcn_mfma_f32_16x16x32_bf16(aF[mi][1], bF[ni][1], acc[4 + mi][ni], 0, 0, 0);
      }
    __builtin_amdgcn_s_setprio(0);
    __builtin_amdgcn_s_barrier();
  }
#undef STAGE_Q
#undef STAGE_A0
#undef STAGE_B0
#undef STAGE_B1
#undef STAGE_A1

  // epilogue (C/D layout: col=lr, row=lh*4+r within fragment)
#pragma unroll
  for (int mi = 0; mi < 8; mi++)
#pragma unroll
    for (int ni = 0; ni < 4; ni++) {
      int row = mBase + rm * 128 + mi * 16 + lh * 4;
      int col = nBase + cn * 64 + ni * 16 + lr;
#pragma unroll
      for (int r = 0; r < 4; r++)
        C[(size_t)(row + r) * N + col] = (OT)acc[mi][ni][r];
    }
}

// ------------------------------ flash attention ------------------------------
// grid (8, h=32, b=2), block 256. Block handles q-tiles blockIdx.x and
// 15-blockIdx.x -> uniform 34 k-tiles/block. Wave w: q rows [qt*128+w*32,+32).
// K/V double-buffered (stage kt+1 before compute of kt; one vmcnt(0)+barrier
// per tile). Ps stride 64 + chunk-XOR (phys_chunk = chunk ^ (row&7)).
// LDS = 32+32+16 = 80 KB -> 2 blocks/CU. Ps is wave-private (no barrier).
__global__ __launch_bounds__(256, 2) void flash_attn(const bf16* __restrict__ qkv,
                                                     const bf16* __restrict__ vt,
                                                     bf16* __restrict__ ao) {
  __shared__ __align__(16) bf16 Ks[2][64 * 128];
  __shared__ __align__(16) bf16 Vts[2][128 * 64];
  __shared__ __align__(16) bf16 Ps[4][32 * 64];
  const int t = threadIdx.x, w = t >> 6, l = t & 63;
  const int lr = l & 15, lh = l >> 4;
  const int h = blockIdx.y, b = blockIdx.z;
  const int hkv = h >> 2;

  // stage K/V tile kt_ into buffer buf_: chunk c = p*256+t;
  // Ks row=c>>4 holds logical chunk (c&15)^(row&15); Vts row=c>>3, ^(row&7).
#define STAGE_KV(kt_, buf_)                                                   \
  do {                                                                        \
    const int kb_ = (kt_) * 64;                                               \
    _Pragma("unroll")                                                         \
    for (int p = 0; p < 4; p++) {                                             \
      int c = p * 256 + t;                                                    \
      int ldsoff = (p * 256 + w * 64) * 8;                                    \
      int krow = c >> 4, kj = (c & 15) ^ (krow & 15);                         \
      load_lds16(qkv + (size_t)(b * 2048 + kb_ + krow) * 6144 + 4096 +        \
                     hkv * 128 + kj * 8,                                      \
                 &Ks[buf_][ldsoff]);                                          \
      int vrow = c >> 3, vj = (c & 7) ^ (vrow & 7);                           \
      load_lds16(vt + ((size_t)(b * 8 + hkv) * 128 + vrow) * 2048 + kb_ +     \
                     vj * 8,                                                  \
                 &Vts[buf_][ldsoff]);                                         \
    }                                                                         \
  } while (0)

  for (int phase = 0; phase < 2; phase++) {
    const int qt = phase == 0 ? blockIdx.x : 15 - blockIdx.x;
    const int qrow0 = qt * 128 + w * 32;
    const int nkt = 2 * qt + 2;

    // prologue: stage tile 0 (prior phase's final barrier already ordered all
    // LDS reads before this overwrite). Q-fragment loads overlap the latency.
    STAGE_KV(0, 0);

    bf16x8 qf[2][4];
#pragma unroll
    for (int rt = 0; rt < 2; rt++)
#pragma unroll
      for (int ds = 0; ds < 4; ds++)
        qf[rt][ds] = *(const bf16x8*)&qkv[(size_t)(b * 2048 + qrow0 + rt * 16 + lr) * 6144 +
                                          h * 128 + ds * 32 + lh * 8];

    f32x4 oacc[2][8] = {};
    float mrow[2][4], lsum[2][4];
#pragma unroll
    for (int rt = 0; rt < 2; rt++)
#pragma unroll
      for (int r = 0; r < 4; r++) { mrow[rt][r] = -3.0e38f; lsum[rt][r] = 0.f; }

    asm volatile("s_waitcnt vmcnt(0)" ::: "memory");
    __builtin_amdgcn_s_barrier();

    for (int kt = 0; kt < nkt; kt++) {
      const int cur = kt & 1;
      const int kbase = kt * 64;
      // prefetch next tile into the other buffer; hides under this tile's
      // QK^T+softmax+PV. Overwrites tile kt-1's data (reads completed >=1
      // barrier ago).
      if (kt + 1 < nkt) STAGE_KV(kt + 1, cur ^ 1);

      // S = Q K^T  (C/D layout: row = rt*16 + lh*4 + r, col = ct*16 + lr)
      f32x4 s[2][4];
      __builtin_amdgcn_s_setprio(1);
#pragma unroll
      for (int ct = 0; ct < 4; ct++) {
        bf16x8 kf[4];
#pragma unroll
        for (int ds = 0; ds < 4; ds++)
          kf[ds] = *(const bf16x8*)&Ks[cur][((ct * 16 + lr) * 16 + ((ds * 4 + lh) ^ lr)) * 8];
#pragma unroll
        for (int rt = 0; rt < 2; rt++) {
          f32x4 acc = {0.f, 0.f, 0.f, 0.f};
#pragma unroll
          for (int ds = 0; ds < 4; ds++)
            acc = __builtin_amdgcn_mfma_f32_16x16x32_bf16(qf[rt][ds], kf[ds], acc, 0, 0, 0);
          s[rt][ct] = acc;
        }
      }
      __builtin_amdgcn_s_setprio(0);

      if (kt >= 2 * qt) {  // diagonal tiles only
#pragma unroll
        for (int rt = 0; rt < 2; rt++)
#pragma unroll
          for (int ct = 0; ct < 4; ct++)
#pragma unroll
            for (int r = 0; r < 4; r++) {
              int qi = qrow0 + rt * 16 + lh * 4 + r;
              int ki = kbase + ct * 16 + lr;
              if (ki > qi) s[rt][ct][r] = -3.0e38f;
            }
      }

      // online softmax (base-2 domain), rows per lane: (rt, r), 16-lane groups
      float alpha[2][4];
#pragma unroll
      for (int rt = 0; rt < 2; rt++)
#pragma unroll
        for (int r = 0; r < 4; r++) {
          float mx = fmaxf(fmaxf(s[rt][0][r], s[rt][1][r]),
                           fmaxf(s[rt][2][r], s[rt][3][r]));
          mx = fmaxf(mx, __shfl_xor(mx, 1));
          mx = fmaxf(mx, __shfl_xor(mx, 2));
          mx = fmaxf(mx, __shfl_xor(mx, 4));
          mx = fmaxf(mx, __shfl_xor(mx, 8));
          float mnew = fmaxf(mrow[rt][r], mx);
          float al = exp2f(mrow[rt][r] - mnew);
          mrow[rt][r] = mnew;
          alpha[rt][r] = al;
          float rs = 0.f;
#pragma unroll
          for (int ct = 0; ct < 4; ct++) {
            float p = exp2f(s[rt][ct][r] - mnew);
            s[rt][ct][r] = p;
            rs += p;
          }
          rs += __shfl_xor(rs, 1);
          rs += __shfl_xor(rs, 2);
          rs += __shfl_xor(rs, 4);
          rs += __shfl_xor(rs, 8);
          lsum[rt][r] = lsum[rt][r] * al + rs;
        }

      // rescale O accumulator
#pragma unroll
      for (int rt = 0; rt < 2; rt++)
#pragma unroll
        for (int dt = 0; dt < 8; dt++)
#pragma unroll
          for (int r = 0; r < 4; r++) oacc[rt][dt][r] *= alpha[rt][r];

      // P: C-layout regs -> LDS (wave-private, chunk-XOR swizzled) -> A frags
#pragma unroll
      for (int rt = 0; rt < 2; rt++)
#pragma unroll
        for (int ct = 0; ct < 4; ct++)
#pragma unroll
          for (int r = 0; r < 4; r++) {
            int row = rt * 16 + lh * 4 + r;
            int col = ct * 16 + lr;
            Ps[w][row * 64 + ((((col >> 3) ^ (row & 7)) << 3) | (col & 7))] =
                (bf16)s[rt][ct][r];
          }
      bf16x8 pf[2][2];
#pragma unroll
      for (int rt = 0; rt < 2; rt++)
#pragma unroll
        for (int ks = 0; ks < 2; ks++)
          pf[rt][ks] = *(const bf16x8*)&Ps[w][(rt * 16 + lr) * 64 +
                                              (((ks * 4 + lh) ^ (lr & 7)) << 3)];

      // O += P V  (B-operand from swizzled Vts: row = d, k-contiguous kpos)
      __builtin_amdgcn_s_setprio(1);
#pragma unroll
      for (int dt = 0; dt < 8; dt++)
#pragma unroll
        for (int ks = 0; ks < 2; ks++) {
          bf16x8 vf = *(const bf16x8*)&Vts[cur][((dt * 16 + lr) * 8 +
                                                 ((ks * 4 + lh) ^ (lr & 7))) * 8];
#pragma unroll
          for (int rt = 0; rt < 2; rt++)
            oacc[rt][dt] =
                __builtin_amdgcn_mfma_f32_16x16x32_bf16(pf[rt][ks], vf, oacc[rt][dt], 0, 0, 0);
        }
      __builtin_amdgcn_s_setprio(0);

      // next tile's data landed (own loads) + all waves' reads of this tile
      // done (consumed via lgkmcnt before MFMA) -> safe to flip buffers.
      asm volatile("s_waitcnt vmcnt(0)" ::: "memory");
      __builtin_amdgcn_s_barrier();
    }

    // epilogue: normalize and store
#pragma unroll
    for (int rt = 0; rt < 2; rt++)
#pragma unroll
      for (int dt = 0; dt < 8; dt++)
#pragma unroll
        for (int r = 0; r < 4; r++) {
          float o = oacc[rt][dt][r] / lsum[rt][r];
          int row = b * 2048 + qrow0 + rt * 16 + lh * 4 + r;
          int col = h * 128 + dt * 16 + lr;
          ao[(size_t)row * 4096 + col] = (bf16)o;
        }
  }
#undef STAGE_KV
}

extern "C" void kernel_launch(void* const* d_in, const int* in_sizes, int n_in,
                              void* d_out, int out_size, void* d_ws, size_t ws_size,
                              hipStream_t stream) {
  const float* x = (const float*)d_in[0];
  const float* wq = (const float*)d_in[1];
  const float* wk = (const float*)d_in[2];
  const float* wv = (const float*)d_in[3];
  const float* wo = (const float*)d_in[4];
  float* out = (float*)d_out;

  char* ws = (char*)d_ws;
  bf16* xb = (bf16*)(ws + 0);
  bf16* wt = (bf16*)(ws + 33554432);       // [6144][4096]: wq^T | wk^T | wv^T
  bf16* wot = (bf16*)(ws + 83886080);      // [4096][4096]
  bf16* qkv = (bf16*)(ws + 117440512);     // [4096][6144]
  bf16* vt = (bf16*)(ws + 167772160);      // [16][128][2048]
  bf16* ao = (bf16*)(ws + 176160768);      // [4096][4096]
  if (ws_size < 209715200u) return;        // need ~210MB scratch

  // 1/sqrt(128) * log2(e): softmax runs natively in exp2 domain
  const float qscale = 0.08838834764831845f * 1.4426950408889634f;

  cast_f32_bf16<<<8192, 256, 0, stream>>>(x, xb, 16777216);
  transpose_cast_all<<<dim3(320, 128), dim3(32, 8), 0, stream>>>(
      wq, wk, wv, wo, wt, wot, qscale);

  gemm_bt8<bf16><<<dim3(24, 16), 512, 0, stream>>>(xb, wt, qkv, 4096, 6144, 4096);
  transpose_v<<<dim3(64, 4, 16), dim3(32, 8), 0, stream>>>(qkv, vt);
  flash_attn<<<dim3(8, 32, 2), 256, 0, stream>>>(qkv, vt, ao);
  gemm_bt8<float><<<dim3(16, 16), 512, 0, stream>>>(ao, wot, out, 4096, 4096, 4096);
}

// Round 6
// 686.599 us; speedup vs baseline: 1.1511x; 1.1511x over previous
//
#include <hip/hip_runtime.h>
#include <cstdint>

// SelfAttention fused pipeline, bf16 MFMA path.
// B=2 S=2048 DIM=4096 HQ=32 HKV=8 D=128, causal, start_pos=0.
//
// R8 changes (first measured round: 790.3 us, flash_attn = 239 us top kernel,
// MfmaUtil 12.6 / VALUBusy 37 / Occ 22 / HBM 8% -> latency-bound on the
// 64-shfl softmax + P-LDS round trip):
//  - flash_attn rewritten to swapped-QK^T 32x32 structure (m214 family):
//    S^T = mfma_32x32x16(K,Q) -> lane owns ONE q-row (col=l&31); row max/sum
//    = 31 lane-local ops + 1 shfl_xor(32) each (was 64 shfl/tile).
//    P^T stays in registers: pb[ks] B-fragments assembled via bf16-pack +
//    2 shfl_xor(32) + cndmask per ks (8 shfl/tile), no Ps LDS buffer.
//    PV computed as O^T = mfma(V^T, P^T) -> alpha/lsum rescale lane-local.
//    LDS 80->64 KB. K/V dbuf staging + swizzles byte-identical (conflict=0).
//  - gemm_bt8, pre/post kernels frozen (gemm dispatch times still unmeasured;
//    both < 237 us from top-5 bound).
//
// ws layout (bytes):
//   xb    @ 0         : bf16[4096][4096]   x cast               (33.5 MB)
//   wt    @ 33554432  : bf16[6144][4096]   [wq^T*scale; wk^T; wv^T] (50.3 MB)
//   wot   @ 83886080  : bf16[4096][4096]   wo^T                 (33.5 MB)
//   qkv   @ 117440512 : bf16[4096][6144]   x@[wq wk wv]         (50.3 MB)
//   vt    @ 167772160 : bf16[2][8][128][2048] V^T per kv head   (8.4 MB)
//   ao    @ 176160768 : bf16[4096][4096]   attention output     (33.5 MB)
// total 209715200 bytes.

typedef __bf16 bf16;
typedef __bf16 bf16x4 __attribute__((ext_vector_type(4)));
typedef __bf16 bf16x8 __attribute__((ext_vector_type(8)));
typedef float f32x4 __attribute__((ext_vector_type(4)));
typedef float f32x16 __attribute__((ext_vector_type(16)));

#define DEV_INLINE __device__ __forceinline__

DEV_INLINE void load_lds16(const bf16* g, bf16* l) {
  // async global->LDS, 16B per lane; LDS dest = wave-uniform base + lane*16
  __builtin_amdgcn_global_load_lds(
      (const __attribute__((address_space(1))) void*)g,
      (__attribute__((address_space(3))) void*)l, 16, 0, 0);
}

DEV_INLINE unsigned pk2(float a, float b) {  // two f32 -> packed bf16 pair
  union { bf16 v[2]; unsigned u; } t;
  t.v[0] = (bf16)a; t.v[1] = (bf16)b;
  return t.u;
}

// ---------------- elementwise cast f32 -> bf16, 8 elems/thread ----------------
__global__ __launch_bounds__(256) void cast_f32_bf16(const float* __restrict__ in,
                                                     bf16* __restrict__ out, int n) {
  int i = (blockIdx.x * 256 + threadIdx.x) * 8;
  if (i >= n) return;
  float4 a = *(const float4*)(in + i);
  float4 b = *(const float4*)(in + i + 4);
  bf16x8 o;
  o[0] = (bf16)a.x; o[1] = (bf16)a.y; o[2] = (bf16)a.z; o[3] = (bf16)a.w;
  o[4] = (bf16)b.x; o[5] = (bf16)b.y; o[6] = (bf16)b.z; o[7] = (bf16)b.w;
  *(bf16x8*)(out + i) = o;
}

// --- merged transpose+cast of all 4 weights: f32 [K=4096][N] -> bf16 [N][4096]
__global__ __launch_bounds__(256) void transpose_cast_all(
    const float* __restrict__ wq, const float* __restrict__ wk,
    const float* __restrict__ wv, const float* __restrict__ wo,
    bf16* __restrict__ wt, bf16* __restrict__ wot, float qscale) {
  __shared__ float t[32][33];
  int bx = blockIdx.x, k0 = blockIdx.y * 32;
  const float* src;
  bf16* dst;
  int N, ncol0, nrow0;
  float scale = 1.0f;
  if (bx < 128) {        // wq -> wt rows [0,4096)
    src = wq; dst = wt; N = 4096; ncol0 = bx * 32; nrow0 = ncol0; scale = qscale;
  } else if (bx < 160) { // wk -> wt rows [4096,5120)
    src = wk; dst = wt; N = 1024; ncol0 = (bx - 128) * 32; nrow0 = 4096 + ncol0;
  } else if (bx < 192) { // wv -> wt rows [5120,6144)
    src = wv; dst = wt; N = 1024; ncol0 = (bx - 160) * 32; nrow0 = 5120 + ncol0;
  } else {               // wo -> wot
    src = wo; dst = wot; N = 4096; ncol0 = (bx - 192) * 32; nrow0 = ncol0;
  }
  int tx = threadIdx.x, ty = threadIdx.y;
#pragma unroll
  for (int i = 0; i < 32; i += 8)
    t[ty + i][tx] = src[(size_t)(k0 + ty + i) * N + ncol0 + tx];
  __syncthreads();
#pragma unroll
  for (int i = 0; i < 32; i += 8)
    dst[(size_t)(nrow0 + ty + i) * 4096 + k0 + tx] = (bf16)(t[tx][ty + i] * scale);
}

// ------ transpose V slice of qkv[4096][6144] -> vt[(b*8+h)*128 + d][2048] -----
__global__ __launch_bounds__(256) void transpose_v(const bf16* __restrict__ qkv,
                                                   bf16* __restrict__ vt) {
  __shared__ bf16 t[32][33];
  int s0 = blockIdx.x * 32, d0 = blockIdx.y * 32, bh = blockIdx.z;
  int b = bh >> 3, h = bh & 7;
  int tx = threadIdx.x, ty = threadIdx.y;
#pragma unroll
  for (int i = 0; i < 32; i += 8)
    t[ty + i][tx] =
        qkv[(size_t)(b * 2048 + s0 + ty + i) * 6144 + 5120 + h * 128 + d0 + tx];
  __syncthreads();
#pragma unroll
  for (int i = 0; i < 32; i += 8)
    vt[((size_t)bh * 128 + d0 + ty + i) * 2048 + s0 + tx] = t[tx][ty + i];
}

// ------------- 8-phase 256^2 GEMM: C[M][N] = A[M][K] * Bt[N][K]^T -------------
// (frozen from R3; see prior round comments for schedule derivation)
template <typename OT>
__global__ __launch_bounds__(512, 2) void gemm_bt8(const bf16* __restrict__ A,
                                                   const bf16* __restrict__ Bt,
                                                   OT* __restrict__ C,
                                                   int M, int N, int K) {
  __shared__ __align__(16) bf16 lds[2][4][128 * 64];
  const int t = threadIdx.x, w = t >> 6, l = t & 63;
  const int lr = l & 15, lh = l >> 4;
  const int rm = w >> 2, cn = w & 3;
  const int mBase = blockIdx.y * 256, nBase = blockIdx.x * 256;
  const int NT = K >> 6;

  size_t gA0[2], gB0[2];
#pragma unroll
  for (int it = 0; it < 2; it++) {
    int c = it * 512 + t;
    int idx = c >> 3;
    int kc = (c & 7) ^ (idx & 7);
    gA0[it] = (size_t)(mBase + (idx >> 6) * 128 + (idx & 63)) * K + kc * 8;
    gB0[it] = (size_t)(nBase + (idx >> 5) * 64 + (idx & 31)) * K + kc * 8;
  }
  const size_t strideA1 = (size_t)64 * K;
  const size_t strideB1 = (size_t)32 * K;
  const int ldst0 = (w * 64) * 8, ldst1 = (512 + w * 64) * 8;

#define STAGE_Q(tile, q, base, off0, off1)                                  \
  do {                                                                      \
    int th_ = (tile);                                                       \
    if (th_ < NT) {                                                         \
      bf16* qb_ = &lds[th_ & 1][q][0];                                      \
      size_t ka_ = (size_t)th_ * 64;                                        \
      load_lds16((base) + (off0) + ka_, qb_ + ldst0);                       \
      load_lds16((base) + (off1) + ka_, qb_ + ldst1);                       \
    }                                                                       \
  } while (0)
#define STAGE_A0(tile) STAGE_Q(tile, 0, A, gA0[0], gA0[1])
#define STAGE_B0(tile) STAGE_Q(tile, 1, Bt, gB0[0], gB0[1])
#define STAGE_B1(tile) STAGE_Q(tile, 2, Bt, gB0[0] + strideB1, gB0[1] + strideB1)
#define STAGE_A1(tile) STAGE_Q(tile, 3, A, gA0[0] + strideA1, gA0[1] + strideA1)

  STAGE_A0(0); STAGE_B0(0); STAGE_B1(0); STAGE_A1(0);
  STAGE_A0(1); STAGE_B0(1); STAGE_B1(1);

  f32x4 acc[8][4] = {};
  bf16x8 aF[4][2], bF[4][2];
  const int rowA = (rm * 64 + lr) * 64;
  const int colB = (cn * 32 + lr) * 64;
  const int xo0 = ((lh ^ (lr & 7)) << 3);
  const int xo1 = (((4 + lh) ^ (lr & 7)) << 3);

  for (int T = 0; T < NT; T++) {
    if (T < NT - 1) asm volatile("s_waitcnt vmcnt(6)" ::: "memory");
    else            asm volatile("s_waitcnt vmcnt(0)" ::: "memory");
    __builtin_amdgcn_s_barrier();
    const bf16* q0 = &lds[T & 1][0][0];
    const bf16* q1 = &lds[T & 1][1][0];
    const bf16* q2 = &lds[T & 1][2][0];
    const bf16* q3 = &lds[T & 1][3][0];

    // ---- phase 0
#pragma unroll
    for (int mi = 0; mi < 4; mi++) {
      aF[mi][0] = *(const bf16x8*)(q0 + rowA + mi * 1024 + xo0);
      aF[mi][1] = *(const bf16x8*)(q0 + rowA + mi * 1024 + xo1);
    }
#pragma unroll
    for (int ni = 0; ni < 2; ni++) {
      bF[ni][0] = *(const bf16x8*)(q1 + colB + ni * 1024 + xo0);
      bF[ni][1] = *(const bf16x8*)(q1 + colB + ni * 1024 + xo1);
    }
    STAGE_A1(T + 1);
    asm volatile("s_waitcnt lgkmcnt(8)" ::: "memory");
    __builtin_amdgcn_s_barrier();
    asm volatile("s_waitcnt lgkmcnt(0)" ::: "memory");
    __builtin_amdgcn_sched_barrier(0);
    __builtin_amdgcn_s_setprio(1);
#pragma unroll
    for (int mi = 0; mi < 4; mi++)
#pragma unroll
      for (int ni = 0; ni < 2; ni++) {
        acc[mi][ni] = __builtin_amdgcn_mfma_f32_16x16x32_bf16(aF[mi][0], bF[ni][0], acc[mi][ni], 0, 0, 0);
        acc[mi][ni] = __builtin_amdgcn_mfma_f32_16x16x32_bf16(aF[mi][1], bF[ni][1], acc[mi][ni], 0, 0, 0);
      }
    __builtin_amdgcn_s_setprio(0);
    __builtin_amdgcn_s_barrier();

    // ---- phase 1
#pragma unroll
    for (int ni = 0; ni < 2; ni++) {
      bF[2 + ni][0] = *(const bf16x8*)(q2 + colB + ni * 1024 + xo0);
      bF[2 + ni][1] = *(const bf16x8*)(q2 + colB + ni * 1024 + xo1);
    }
    STAGE_A0(T + 2);
    __builtin_amdgcn_s_barrier();
    asm volatile("s_waitcnt lgkmcnt(0)" ::: "memory");
    __builtin_amdgcn_sched_barrier(0);
    __builtin_amdgcn_s_setprio(1);
#pragma unroll
    for (int mi = 0; mi < 4; mi++)
#pragma unroll
      for (int ni = 2; ni < 4; ni++) {
        acc[mi][ni] = __builtin_amdgcn_mfma_f32_16x16x32_bf16(aF[mi][0], bF[ni][0], acc[mi][ni], 0, 0, 0);
        acc[mi][ni] = __builtin_amdgcn_mfma_f32_16x16x32_bf16(aF[mi][1], bF[ni][1], acc[mi][ni], 0, 0, 0);
      }
    __builtin_amdgcn_s_setprio(0);
    __builtin_amdgcn_s_barrier();

    // ---- phase 2
#pragma unroll
    for (int mi = 0; mi < 4; mi++) {
      aF[mi][0] = *(const bf16x8*)(q3 + rowA + mi * 1024 + xo0);
      aF[mi][1] = *(const bf16x8*)(q3 + rowA + mi * 1024 + xo1);
    }
    STAGE_B0(T + 2);
    __builtin_amdgcn_s_barrier();
    asm volatile("s_waitcnt lgkmcnt(0)" ::: "memory");
    __builtin_amdgcn_sched_barrier(0);
    __builtin_amdgcn_s_setprio(1);
#pragma unroll
    for (int mi = 0; mi < 4; mi++)
#pragma unroll
      for (int ni = 0; ni < 2; ni++) {
        acc[4 + mi][ni] = __builtin_amdgcn_mfma_f32_16x16x32_bf16(aF[mi][0], bF[ni][0], acc[4 + mi][ni], 0, 0, 0);
        acc[4 + mi][ni] = __builtin_amdgcn_mfma_f32_16x16x32_bf16(aF[mi][1], bF[ni][1], acc[4 + mi][ni], 0, 0, 0);
      }
    __builtin_amdgcn_s_setprio(0);
    __builtin_amdgcn_s_barrier();

    // ---- phase 3
    STAGE_B1(T + 2);
    __builtin_amdgcn_s_barrier();
    __builtin_amdgcn_s_setprio(1);
#pragma unroll
    for (int mi = 0; mi < 4; mi++)
#pragma unroll
      for (int ni = 2; ni < 4; ni++) {
        acc[4 + mi][ni] = __builtin_amdgcn_mfma_f32_16x16x32_bf16(aF[mi][0], bF[ni][0], acc[4 + mi][ni], 0, 0, 0);
        acc[4 + mi][ni] = __builtin_amdgcn_mfma_f32_16x16x32_bf16(aF[mi][1], bF[ni][1], acc[4 + mi][ni], 0, 0, 0);
      }
    __builtin_amdgcn_s_setprio(0);
    __builtin_amdgcn_s_barrier();
  }
#undef STAGE_Q
#undef STAGE_A0
#undef STAGE_B0
#undef STAGE_B1
#undef STAGE_A1

#pragma unroll
  for (int mi = 0; mi < 8; mi++)
#pragma unroll
    for (int ni = 0; ni < 4; ni++) {
      int row = mBase + rm * 128 + mi * 16 + lh * 4;
      int col = nBase + cn * 64 + ni * 16 + lr;
#pragma unroll
      for (int r = 0; r < 4; r++)
        C[(size_t)(row + r) * N + col] = (OT)acc[mi][ni][r];
    }
}

// ------------------------------ flash attention ------------------------------
// grid (8, h=32, b=2), block 256. Block handles q-tiles blockIdx.x and
// 15-blockIdx.x -> uniform 34 k-tiles/block. Wave w: q rows [qt*128+w*32,+32).
// Swapped-QK^T 32x32 structure: S^T[k][q] = mfma_32x32x16(K, Q); lane owns
// q = qrow0 + (l&31); its 64 k-values split across lane pair (l, l^32) via
// C/D map k = ct*32 + (reg&3) + 8*(reg>>2) + 4*hi. Softmax = 31 lane-local
// ops + 1 shfl_xor(32) per quantity. P^T stays in registers: pb[ks]
// (B-operand, col=q=l&31, k=hi*8+j) assembled with pk2 + 2 shfl_xor(32) +
// cndmask per ks. PV: O^T[d][q] = mfma(V^T, P^T) -> rescale lane-local.
// K/V dbuf staging identical to R5 (measured conflict-free). LDS 64 KB.
__global__ __launch_bounds__(256, 2) void flash_attn(const bf16* __restrict__ qkv,
                                                     const bf16* __restrict__ vt,
                                                     bf16* __restrict__ ao) {
  __shared__ __align__(16) bf16 Ks[2][64 * 128];
  __shared__ __align__(16) bf16 Vts[2][128 * 64];
  const int t = threadIdx.x, w = t >> 6, l = t & 63;
  const int l31 = l & 31, hi = l >> 5;
  const int h = blockIdx.y, b = blockIdx.z;
  const int hkv = h >> 2;

  // stage K/V tile kt_ into buffer buf_: chunk c = p*256+t;
  // Ks row=c>>4 holds logical chunk (c&15)^(row&15); Vts row=c>>3, ^(row&7).
#define STAGE_KV(kt_, buf_)                                                   \
  do {                                                                        \
    const int kb_ = (kt_) * 64;                                               \
    _Pragma("unroll")                                                         \
    for (int p = 0; p < 4; p++) {                                             \
      int c = p * 256 + t;                                                    \
      int ldsoff = (p * 256 + w * 64) * 8;                                    \
      int krow = c >> 4, kj = (c & 15) ^ (krow & 15);                         \
      load_lds16(qkv + (size_t)(b * 2048 + kb_ + krow) * 6144 + 4096 +        \
                     hkv * 128 + kj * 8,                                      \
                 &Ks[buf_][ldsoff]);                                          \
      int vrow = c >> 3, vj = (c & 7) ^ (vrow & 7);                           \
      load_lds16(vt + ((size_t)(b * 8 + hkv) * 128 + vrow) * 2048 + kb_ +     \
                     vj * 8,                                                  \
                 &Vts[buf_][ldsoff]);                                         \
    }                                                                         \
  } while (0)

  for (int phase = 0; phase < 2; phase++) {
    const int qt = phase == 0 ? blockIdx.x : 15 - blockIdx.x;
    const int qrow0 = qt * 128 + w * 32;
    const int nkt = 2 * qt + 2;
    const int q = qrow0 + l31;  // this lane's q row (shared with lane l^32)

    // prologue: stage tile 0 (prior phase's final barrier ordered all LDS
    // reads before this overwrite). Q-fragment loads overlap the latency.
    STAGE_KV(0, 0);

    // Q as B-operand: col = q = l31, contraction-d = d0*16 + hi*8 + j
    bf16x8 qf[8];
#pragma unroll
    for (int d0 = 0; d0 < 8; d0++)
      qf[d0] = *(const bf16x8*)&qkv[(size_t)(b * 2048 + q) * 6144 + h * 128 +
                                    d0 * 16 + hi * 8];

    f32x16 oacc[4] = {};  // O^T: oacc[db][reg], d = db*32+(reg&3)+8*(reg>>2)+4*hi
    float mrow = -3.0e38f, lsum = 0.f;

    asm volatile("s_waitcnt vmcnt(0)" ::: "memory");
    __builtin_amdgcn_s_barrier();

    for (int kt = 0; kt < nkt; kt++) {
      const int cur = kt & 1;
      const int kbase = kt * 64;
      if (kt + 1 < nkt) STAGE_KV(kt + 1, cur ^ 1);

      // S^T = K Q^T: s[ct][reg] = P-logit[q][k = kbase+ct*32+(reg&3)+8*(reg>>2)+4*hi]
      f32x16 s[2] = {};
      __builtin_amdgcn_s_setprio(1);
#pragma unroll
      for (int d0 = 0; d0 < 8; d0++)
#pragma unroll
        for (int ct = 0; ct < 2; ct++) {
          int krow = ct * 32 + l31;
          bf16x8 kf = *(const bf16x8*)&Ks[cur][(krow * 16 +
                                                ((d0 * 2 + hi) ^ (krow & 15))) * 8];
          s[ct] = __builtin_amdgcn_mfma_f32_32x32x16_bf16(kf, qf[d0], s[ct], 0, 0, 0);
        }
      __builtin_amdgcn_s_setprio(0);

      if (kt >= 2 * qt) {  // diagonal tiles only
#pragma unroll
        for (int ct = 0; ct < 2; ct++)
#pragma unroll
          for (int reg = 0; reg < 16; reg++) {
            int ki = kbase + ct * 32 + (reg & 3) + 8 * (reg >> 2) + 4 * hi;
            if (ki > q) s[ct][reg] = -3.0e38f;
          }
      }

      // online softmax (base-2 domain), lane-local row + 1 shfl per quantity
      float tm[16];
#pragma unroll
      for (int i = 0; i < 16; i++) tm[i] = fmaxf(s[0][i], s[1][i]);
#pragma unroll
      for (int st = 8; st > 0; st >>= 1)
#pragma unroll
        for (int i = 0; i < 8; i++)
          if (i < st) tm[i] = fmaxf(tm[i], tm[i + st]);
      float mx = fmaxf(tm[0], __shfl_xor(tm[0], 32));
      float mnew = fmaxf(mrow, mx);
      float al = exp2f(mrow - mnew);
      mrow = mnew;
#pragma unroll
      for (int ct = 0; ct < 2; ct++)
#pragma unroll
        for (int reg = 0; reg < 16; reg++) s[ct][reg] = exp2f(s[ct][reg] - mnew);
      float ts[16];
#pragma unroll
      for (int i = 0; i < 16; i++) ts[i] = s[0][i] + s[1][i];
#pragma unroll
      for (int st = 8; st > 0; st >>= 1)
#pragma unroll
        for (int i = 0; i < 8; i++)
          if (i < st) ts[i] = ts[i] + ts[i + st];
      float rs = ts[0] + __shfl_xor(ts[0], 32);
      lsum = lsum * al + rs;

      // rescale O^T (lane-local: all regs share this lane's q)
#pragma unroll
      for (int db = 0; db < 4; db++)
#pragma unroll
        for (int reg = 0; reg < 16; reg++) oacc[db][reg] *= al;

      // P^T B-fragments: pb[ks][j] = P[q][ks*16 + hi*8 + j].
      // Own reg-quad 2*s1 supplies half; partner (l^32) quad supplies other.
      bf16x8 pb[4];
#pragma unroll
      for (int ks = 0; ks < 4; ks++) {
        const int ct = ks >> 1, s1 = ks & 1;
        unsigned A0 = pk2(s[ct][(2 * s1) * 4 + 0], s[ct][(2 * s1) * 4 + 1]);
        unsigned A1 = pk2(s[ct][(2 * s1) * 4 + 2], s[ct][(2 * s1) * 4 + 3]);
        unsigned B0 = pk2(s[ct][(2 * s1 + 1) * 4 + 0], s[ct][(2 * s1 + 1) * 4 + 1]);
        unsigned B1 = pk2(s[ct][(2 * s1 + 1) * 4 + 2], s[ct][(2 * s1 + 1) * 4 + 3]);
        unsigned z0 = hi ? A0 : B0, z1 = hi ? A1 : B1;   // what partner needs of us
        unsigned x0 = __shfl_xor(z0, 32), x1 = __shfl_xor(z1, 32);
        union { unsigned u[4]; bf16x8 v; } pw;
        pw.u[0] = hi ? x0 : A0;
        pw.u[1] = hi ? x1 : A1;
        pw.u[2] = hi ? B0 : x0;
        pw.u[3] = hi ? B1 : x1;
        pb[ks] = pw.v;
      }

      // O^T += V^T P^T  (A = V^T: row = d = db*32+l31, k = hi*8+j)
      __builtin_amdgcn_s_setprio(1);
#pragma unroll
      for (int ks = 0; ks < 4; ks++)
#pragma unroll
        for (int db = 0; db < 4; db++) {
          int vr = db * 32 + l31;
          bf16x8 vf = *(const bf16x8*)&Vts[cur][(vr * 8 +
                                                 ((ks * 2 + hi) ^ (vr & 7))) * 8];
          oacc[db] = __builtin_amdgcn_mfma_f32_32x32x16_bf16(vf, pb[ks], oacc[db], 0, 0, 0);
        }
      __builtin_amdgcn_s_setprio(0);

      asm volatile("s_waitcnt vmcnt(0)" ::: "memory");
      __builtin_amdgcn_s_barrier();
    }

    // epilogue: normalize, transpose-free store (4 consecutive d per reg-quad)
    float inv = 1.0f / lsum;
#pragma unroll
    for (int db = 0; db < 4; db++)
#pragma unroll
      for (int q4 = 0; q4 < 4; q4++) {
        bf16x4 o4;
#pragma unroll
        for (int j = 0; j < 4; j++) o4[j] = (bf16)(oacc[db][q4 * 4 + j] * inv);
        int d0 = db * 32 + q4 * 8 + hi * 4;
        *(bf16x4*)&ao[(size_t)(b * 2048 + q) * 4096 + h * 128 + d0] = o4;
      }
  }
#undef STAGE_KV
}

extern "C" void kernel_launch(void* const* d_in, const int* in_sizes, int n_in,
                              void* d_out, int out_size, void* d_ws, size_t ws_size,
                              hipStream_t stream) {
  const float* x = (const float*)d_in[0];
  const float* wq = (const float*)d_in[1];
  const float* wk = (const float*)d_in[2];
  const float* wv = (const float*)d_in[3];
  const float* wo = (const float*)d_in[4];
  float* out = (float*)d_out;

  char* ws = (char*)d_ws;
  bf16* xb = (bf16*)(ws + 0);
  bf16* wt = (bf16*)(ws + 33554432);       // [6144][4096]: wq^T | wk^T | wv^T
  bf16* wot = (bf16*)(ws + 83886080);      // [4096][4096]
  bf16* qkv = (bf16*)(ws + 117440512);     // [4096][6144]
  bf16* vt = (bf16*)(ws + 167772160);      // [16][128][2048]
  bf16* ao = (bf16*)(ws + 176160768);      // [4096][4096]
  if (ws_size < 209715200u) return;        // need ~210MB scratch

  // 1/sqrt(128) * log2(e): softmax runs natively in exp2 domain
  const float qscale = 0.08838834764831845f * 1.4426950408889634f;

  cast_f32_bf16<<<8192, 256, 0, stream>>>(x, xb, 16777216);
  transpose_cast_all<<<dim3(320, 128), dim3(32, 8), 0, stream>>>(
      wq, wk, wv, wo, wt, wot, qscale);

  gemm_bt8<bf16><<<dim3(24, 16), 512, 0, stream>>>(xb, wt, qkv, 4096, 6144, 4096);
  transpose_v<<<dim3(64, 4, 16), dim3(32, 8), 0, stream>>>(qkv, vt);
  flash_attn<<<dim3(8, 32, 2), 256, 0, stream>>>(qkv, vt, ao);
  gemm_bt8<float><<<dim3(16, 16), 512, 0, stream>>>(ao, wot, out, 4096, 4096, 4096);
}

// Round 7
// 667.744 us; speedup vs baseline: 1.1836x; 1.0282x over previous
//
#include <hip/hip_runtime.h>
#include <cstdint>

// SelfAttention fused pipeline, bf16 MFMA path.
// B=2 S=2048 DIM=4096 HQ=32 HKV=8 D=128, causal, start_pos=0.
//
// R9 changes (measured R8: 686.6 us; gemm_bt8<bf16> now top at 235 us,
// MfmaUtil 37% = m198-level despite 0 bank conflicts -> barrier-lockstep
// diagnosis: 8 barriers/tile, reads never overlap MFMA):
//  - gemm_bt8 K-loop restructured to TWO barriers per tile:
//      top:  vmcnt(6)+barrier (all DMA for tile T landed, cross-wave)
//      mid:  sched_barrier(0); s_barrier; sched_barrier(0)  — separates
//            {top reads Q0/Q1, p0 reads Q2} from same-buffer stages
//            A0/B0/B1(T+2). Q3 reads (post-mid) protected by T+1's top
//            barrier (A1(T+2) stages after it).
//    All manual lgkmcnt dropped — plain C++ ds_reads let hipcc emit
//    fine-grained lgkmcnt so reads issue under MFMA. aF register set
//    reused for A-h0 (p0/p1) then A-h1 (p2/p3): frags stay 64 VGPR.
//    MFMA groups ks-outer (8 independent chains first). vmcnt ledger and
//    per-wave stage order (A1,A0,B0,B1) unchanged from R3 (re-audited).
//  - flash_attn (R8 swapped-QK^T 32x32, in-register softmax) frozen.
//
// ws layout (bytes):
//   xb    @ 0         : bf16[4096][4096]   x cast               (33.5 MB)
//   wt    @ 33554432  : bf16[6144][4096]   [wq^T*scale; wk^T; wv^T] (50.3 MB)
//   wot   @ 83886080  : bf16[4096][4096]   wo^T                 (33.5 MB)
//   qkv   @ 117440512 : bf16[4096][6144]   x@[wq wk wv]         (50.3 MB)
//   vt    @ 167772160 : bf16[2][8][128][2048] V^T per kv head   (8.4 MB)
//   ao    @ 176160768 : bf16[4096][4096]   attention output     (33.5 MB)
// total 209715200 bytes.

typedef __bf16 bf16;
typedef __bf16 bf16x4 __attribute__((ext_vector_type(4)));
typedef __bf16 bf16x8 __attribute__((ext_vector_type(8)));
typedef float f32x4 __attribute__((ext_vector_type(4)));
typedef float f32x16 __attribute__((ext_vector_type(16)));

#define DEV_INLINE __device__ __forceinline__

DEV_INLINE void load_lds16(const bf16* g, bf16* l) {
  // async global->LDS, 16B per lane; LDS dest = wave-uniform base + lane*16
  __builtin_amdgcn_global_load_lds(
      (const __attribute__((address_space(1))) void*)g,
      (__attribute__((address_space(3))) void*)l, 16, 0, 0);
}

DEV_INLINE unsigned pk2(float a, float b) {  // two f32 -> packed bf16 pair
  union { bf16 v[2]; unsigned u; } t;
  t.v[0] = (bf16)a; t.v[1] = (bf16)b;
  return t.u;
}

// ---------------- elementwise cast f32 -> bf16, 8 elems/thread ----------------
__global__ __launch_bounds__(256) void cast_f32_bf16(const float* __restrict__ in,
                                                     bf16* __restrict__ out, int n) {
  int i = (blockIdx.x * 256 + threadIdx.x) * 8;
  if (i >= n) return;
  float4 a = *(const float4*)(in + i);
  float4 b = *(const float4*)(in + i + 4);
  bf16x8 o;
  o[0] = (bf16)a.x; o[1] = (bf16)a.y; o[2] = (bf16)a.z; o[3] = (bf16)a.w;
  o[4] = (bf16)b.x; o[5] = (bf16)b.y; o[6] = (bf16)b.z; o[7] = (bf16)b.w;
  *(bf16x8*)(out + i) = o;
}

// --- merged transpose+cast of all 4 weights: f32 [K=4096][N] -> bf16 [N][4096]
__global__ __launch_bounds__(256) void transpose_cast_all(
    const float* __restrict__ wq, const float* __restrict__ wk,
    const float* __restrict__ wv, const float* __restrict__ wo,
    bf16* __restrict__ wt, bf16* __restrict__ wot, float qscale) {
  __shared__ float t[32][33];
  int bx = blockIdx.x, k0 = blockIdx.y * 32;
  const float* src;
  bf16* dst;
  int N, ncol0, nrow0;
  float scale = 1.0f;
  if (bx < 128) {        // wq -> wt rows [0,4096)
    src = wq; dst = wt; N = 4096; ncol0 = bx * 32; nrow0 = ncol0; scale = qscale;
  } else if (bx < 160) { // wk -> wt rows [4096,5120)
    src = wk; dst = wt; N = 1024; ncol0 = (bx - 128) * 32; nrow0 = 4096 + ncol0;
  } else if (bx < 192) { // wv -> wt rows [5120,6144)
    src = wv; dst = wt; N = 1024; ncol0 = (bx - 160) * 32; nrow0 = 5120 + ncol0;
  } else {               // wo -> wot
    src = wo; dst = wot; N = 4096; ncol0 = (bx - 192) * 32; nrow0 = ncol0;
  }
  int tx = threadIdx.x, ty = threadIdx.y;
#pragma unroll
  for (int i = 0; i < 32; i += 8)
    t[ty + i][tx] = src[(size_t)(k0 + ty + i) * N + ncol0 + tx];
  __syncthreads();
#pragma unroll
  for (int i = 0; i < 32; i += 8)
    dst[(size_t)(nrow0 + ty + i) * 4096 + k0 + tx] = (bf16)(t[tx][ty + i] * scale);
}

// ------ transpose V slice of qkv[4096][6144] -> vt[(b*8+h)*128 + d][2048] -----
__global__ __launch_bounds__(256) void transpose_v(const bf16* __restrict__ qkv,
                                                   bf16* __restrict__ vt) {
  __shared__ bf16 t[32][33];
  int s0 = blockIdx.x * 32, d0 = blockIdx.y * 32, bh = blockIdx.z;
  int b = bh >> 3, h = bh & 7;
  int tx = threadIdx.x, ty = threadIdx.y;
#pragma unroll
  for (int i = 0; i < 32; i += 8)
    t[ty + i][tx] =
        qkv[(size_t)(b * 2048 + s0 + ty + i) * 6144 + 5120 + h * 128 + d0 + tx];
  __syncthreads();
#pragma unroll
  for (int i = 0; i < 32; i += 8)
    vt[((size_t)bh * 128 + d0 + ty + i) * 2048 + s0 + tx] = t[tx][ty + i];
}

// ------------- 2-barrier 256^2 GEMM: C[M][N] = A[M][K] * Bt[N][K]^T ----------
// 512 threads, waves (rm=w>>2 in 2, cn=w&3 in 4); per-wave C = 128x64.
// LDS quarters per dbuf (16 KB each, [128 idx][64 K] bf16, XOR-swizzled
// chunk' = chunk ^ (idx&7)): Q0=A-h0, Q1=B-n01, Q2=B-n23, Q3=A-h1.
// Per tile: top { vmcnt(6)|0 ; barrier ; read aF<-Q0, bLo<-Q1 ; STAGE_A1(T+1) }
//   p0 MFMA aF x bLo -> acc[0..3][0..1] ; read bHi<-Q2
//   MID barrier (sched-pinned)  ; STAGE_A0(T+2)
//   p1 MFMA aF x bHi -> acc[0..3][2..3] ; read aF<-Q3 (A-h1, WAR reuse)
//   STAGE_B0(T+2)
//   p2 MFMA aF x bLo -> acc[4..7][0..1]
//   STAGE_B1(T+2)
//   p3 MFMA aF x bHi -> acc[4..7][2..3]
// Race audit: Q0/Q1 reads (top) and Q2 reads (p0) precede MID barrier;
// their same-buffer overwrites A0/B0/B1(T+2) are staged after it. Q3 reads
// (post-MID) precede T+1's TOP barrier; overwrite A1(T+2) stages after it.
// vmcnt ledger identical to R3 (stage order A1,A0,B0,B1; vmcnt(6) at top
// retires exactly tile T's 4 quarters; vmcnt(0) last tile).
template <typename OT>
__global__ __launch_bounds__(512, 2) void gemm_bt8(const bf16* __restrict__ A,
                                                   const bf16* __restrict__ Bt,
                                                   OT* __restrict__ C,
                                                   int M, int N, int K) {
  __shared__ __align__(16) bf16 lds[2][4][128 * 64];
  const int t = threadIdx.x, w = t >> 6, l = t & 63;
  const int lr = l & 15, lh = l >> 4;
  const int rm = w >> 2, cn = w & 3;
  const int mBase = blockIdx.y * 256, nBase = blockIdx.x * 256;
  const int NT = K >> 6;

  // per-thread DMA source offsets (elements) for the two 512-chunk passes
  size_t gA0[2], gB0[2];
#pragma unroll
  for (int it = 0; it < 2; it++) {
    int c = it * 512 + t;            // 16B chunk id in [0,1024)
    int idx = c >> 3;                // LDS row within quarter
    int kc = (c & 7) ^ (idx & 7);    // logical K-chunk (8 els) stored here
    gA0[it] = (size_t)(mBase + (idx >> 6) * 128 + (idx & 63)) * K + kc * 8;
    gB0[it] = (size_t)(nBase + (idx >> 5) * 64 + (idx & 31)) * K + kc * 8;
  }
  const size_t strideA1 = (size_t)64 * K;   // +64 rows  (mih1)
  const size_t strideB1 = (size_t)32 * K;   // +32 cols  (nih1)
  const int ldst0 = (w * 64) * 8, ldst1 = (512 + w * 64) * 8;  // element offs

#define STAGE_Q(tile, q, base, off0, off1)                                  \
  do {                                                                      \
    int th_ = (tile);                                                       \
    if (th_ < NT) {                                                         \
      bf16* qb_ = &lds[th_ & 1][q][0];                                      \
      size_t ka_ = (size_t)th_ * 64;                                        \
      load_lds16((base) + (off0) + ka_, qb_ + ldst0);                       \
      load_lds16((base) + (off1) + ka_, qb_ + ldst1);                       \
    }                                                                       \
  } while (0)
#define STAGE_A0(tile) STAGE_Q(tile, 0, A, gA0[0], gA0[1])
#define STAGE_B0(tile) STAGE_Q(tile, 1, Bt, gB0[0], gB0[1])
#define STAGE_B1(tile) STAGE_Q(tile, 2, Bt, gB0[0] + strideB1, gB0[1] + strideB1)
#define STAGE_A1(tile) STAGE_Q(tile, 3, A, gA0[0] + strideA1, gA0[1] + strideA1)

  // prologue: stream h=0..6  (tile0 Q0,Q1,Q2,Q3; tile1 Q0,Q1,Q2)
  STAGE_A0(0); STAGE_B0(0); STAGE_B1(0); STAGE_A1(0);
  STAGE_A0(1); STAGE_B0(1); STAGE_B1(1);

  f32x4 acc[8][4] = {};
  bf16x8 aF[4][2], bLo[2][2], bHi[2][2];
  // read-side addressing: idx&7 == lr&7 for all fragment reads
  const int rowA = (rm * 64 + lr) * 64;               // element off, mi=0
  const int colB = (cn * 32 + lr) * 64;               // element off, ni even
  const int xo0 = ((lh ^ (lr & 7)) << 3);             // ks=0 swizzled K-off
  const int xo1 = (((4 + lh) ^ (lr & 7)) << 3);       // ks=1

  for (int T = 0; T < NT; T++) {
    // ---- tile top: all DMA for tile T landed (cross-wave via barrier)
    if (T < NT - 1) asm volatile("s_waitcnt vmcnt(6)" ::: "memory");
    else            asm volatile("s_waitcnt vmcnt(0)" ::: "memory");
    __builtin_amdgcn_s_barrier();
    const bf16* q0 = &lds[T & 1][0][0];
    const bf16* q1 = &lds[T & 1][1][0];
    const bf16* q2 = &lds[T & 1][2][0];
    const bf16* q3 = &lds[T & 1][3][0];

    // top reads: A-h0 and B-n01 fragments (compiler inserts lgkmcnt)
#pragma unroll
    for (int mi = 0; mi < 4; mi++) {
      aF[mi][0] = *(const bf16x8*)(q0 + rowA + mi * 1024 + xo0);
      aF[mi][1] = *(const bf16x8*)(q0 + rowA + mi * 1024 + xo1);
    }
#pragma unroll
    for (int ni = 0; ni < 2; ni++) {
      bLo[ni][0] = *(const bf16x8*)(q1 + colB + ni * 1024 + xo0);
      bLo[ni][1] = *(const bf16x8*)(q1 + colB + ni * 1024 + xo1);
    }
    STAGE_A1(T + 1);

    // p0: acc[0..3][0..1] += aF(A-h0) x bLo   (ks-outer: 8 indep chains)
    __builtin_amdgcn_s_setprio(1);
#pragma unroll
    for (int ks = 0; ks < 2; ks++)
#pragma unroll
      for (int mi = 0; mi < 4; mi++)
#pragma unroll
        for (int ni = 0; ni < 2; ni++)
          acc[mi][ni] = __builtin_amdgcn_mfma_f32_16x16x32_bf16(
              aF[mi][ks], bLo[ni][ks], acc[mi][ni], 0, 0, 0);
    __builtin_amdgcn_s_setprio(0);
    // read B-n23 (tile T) — must issue before MID barrier
#pragma unroll
    for (int ni = 0; ni < 2; ni++) {
      bHi[ni][0] = *(const bf16x8*)(q2 + colB + ni * 1024 + xo0);
      bHi[ni][1] = *(const bf16x8*)(q2 + colB + ni * 1024 + xo1);
    }

    // ---- MID barrier: separates tile-T reads of Q0/Q1/Q2 from their
    // same-buffer overwriting stages (T+2). sched_barrier pins both sides.
    __builtin_amdgcn_sched_barrier(0);
    __builtin_amdgcn_s_barrier();
    __builtin_amdgcn_sched_barrier(0);
    STAGE_A0(T + 2);

    // p1: acc[0..3][2..3] += aF(A-h0) x bHi
    __builtin_amdgcn_s_setprio(1);
#pragma unroll
    for (int ks = 0; ks < 2; ks++)
#pragma unroll
      for (int mi = 0; mi < 4; mi++)
#pragma unroll
        for (int ni = 0; ni < 2; ni++)
          acc[mi][2 + ni] = __builtin_amdgcn_mfma_f32_16x16x32_bf16(
              aF[mi][ks], bHi[ni][ks], acc[mi][2 + ni], 0, 0, 0);
    __builtin_amdgcn_s_setprio(0);
    // read A-h1 into aF (WAR reuse; in-order wave makes this safe).
    // Protected from overwrite (A1(T+2), staged after T+1's top barrier).
#pragma unroll
    for (int mi = 0; mi < 4; mi++) {
      aF[mi][0] = *(const bf16x8*)(q3 + rowA + mi * 1024 + xo0);
      aF[mi][1] = *(const bf16x8*)(q3 + rowA + mi * 1024 + xo1);
    }
    STAGE_B0(T + 2);

    // p2: acc[4..7][0..1] += aF(A-h1) x bLo
    __builtin_amdgcn_s_setprio(1);
#pragma unroll
    for (int ks = 0; ks < 2; ks++)
#pragma unroll
      for (int mi = 0; mi < 4; mi++)
#pragma unroll
        for (int ni = 0; ni < 2; ni++)
          acc[4 + mi][ni] = __builtin_amdgcn_mfma_f32_16x16x32_bf16(
              aF[mi][ks], bLo[ni][ks], acc[4 + mi][ni], 0, 0, 0);
    __builtin_amdgcn_s_setprio(0);
    STAGE_B1(T + 2);

    // p3: acc[4..7][2..3] += aF(A-h1) x bHi
    __builtin_amdgcn_s_setprio(1);
#pragma unroll
    for (int ks = 0; ks < 2; ks++)
#pragma unroll
      for (int mi = 0; mi < 4; mi++)
#pragma unroll
        for (int ni = 0; ni < 2; ni++)
          acc[4 + mi][2 + ni] = __builtin_amdgcn_mfma_f32_16x16x32_bf16(
              aF[mi][ks], bHi[ni][ks], acc[4 + mi][2 + ni], 0, 0, 0);
    __builtin_amdgcn_s_setprio(0);
  }
#undef STAGE_Q
#undef STAGE_A0
#undef STAGE_B0
#undef STAGE_B1
#undef STAGE_A1

  // epilogue (C/D layout: col=lr, row=lh*4+r within fragment)
#pragma unroll
  for (int mi = 0; mi < 8; mi++)
#pragma unroll
    for (int ni = 0; ni < 4; ni++) {
      int row = mBase + rm * 128 + mi * 16 + lh * 4;
      int col = nBase + cn * 64 + ni * 16 + lr;
#pragma unroll
      for (int r = 0; r < 4; r++)
        C[(size_t)(row + r) * N + col] = (OT)acc[mi][ni][r];
    }
}

// ------------------------------ flash attention ------------------------------
// (frozen from R8 — swapped-QK^T 32x32, in-register softmax, K/V dbuf, 64 KB)
__global__ __launch_bounds__(256, 2) void flash_attn(const bf16* __restrict__ qkv,
                                                     const bf16* __restrict__ vt,
                                                     bf16* __restrict__ ao) {
  __shared__ __align__(16) bf16 Ks[2][64 * 128];
  __shared__ __align__(16) bf16 Vts[2][128 * 64];
  const int t = threadIdx.x, w = t >> 6, l = t & 63;
  const int l31 = l & 31, hi = l >> 5;
  const int h = blockIdx.y, b = blockIdx.z;
  const int hkv = h >> 2;

#define STAGE_KV(kt_, buf_)                                                   \
  do {                                                                        \
    const int kb_ = (kt_) * 64;                                               \
    _Pragma("unroll")                                                         \
    for (int p = 0; p < 4; p++) {                                             \
      int c = p * 256 + t;                                                    \
      int ldsoff = (p * 256 + w * 64) * 8;                                    \
      int krow = c >> 4, kj = (c & 15) ^ (krow & 15);                         \
      load_lds16(qkv + (size_t)(b * 2048 + kb_ + krow) * 6144 + 4096 +        \
                     hkv * 128 + kj * 8,                                      \
                 &Ks[buf_][ldsoff]);                                          \
      int vrow = c >> 3, vj = (c & 7) ^ (vrow & 7);                           \
      load_lds16(vt + ((size_t)(b * 8 + hkv) * 128 + vrow) * 2048 + kb_ +     \
                     vj * 8,                                                  \
                 &Vts[buf_][ldsoff]);                                         \
    }                                                                         \
  } while (0)

  for (int phase = 0; phase < 2; phase++) {
    const int qt = phase == 0 ? blockIdx.x : 15 - blockIdx.x;
    const int qrow0 = qt * 128 + w * 32;
    const int nkt = 2 * qt + 2;
    const int q = qrow0 + l31;  // this lane's q row (shared with lane l^32)

    STAGE_KV(0, 0);

    // Q as B-operand: col = q = l31, contraction-d = d0*16 + hi*8 + j
    bf16x8 qf[8];
#pragma unroll
    for (int d0 = 0; d0 < 8; d0++)
      qf[d0] = *(const bf16x8*)&qkv[(size_t)(b * 2048 + q) * 6144 + h * 128 +
                                    d0 * 16 + hi * 8];

    f32x16 oacc[4] = {};  // O^T: oacc[db][reg], d = db*32+(reg&3)+8*(reg>>2)+4*hi
    float mrow = -3.0e38f, lsum = 0.f;

    asm volatile("s_waitcnt vmcnt(0)" ::: "memory");
    __builtin_amdgcn_s_barrier();

    for (int kt = 0; kt < nkt; kt++) {
      const int cur = kt & 1;
      const int kbase = kt * 64;
      if (kt + 1 < nkt) STAGE_KV(kt + 1, cur ^ 1);

      // S^T = K Q^T: s[ct][reg], k = kbase+ct*32+(reg&3)+8*(reg>>2)+4*hi
      f32x16 s[2] = {};
      __builtin_amdgcn_s_setprio(1);
#pragma unroll
      for (int d0 = 0; d0 < 8; d0++)
#pragma unroll
        for (int ct = 0; ct < 2; ct++) {
          int krow = ct * 32 + l31;
          bf16x8 kf = *(const bf16x8*)&Ks[cur][(krow * 16 +
                                                ((d0 * 2 + hi) ^ (krow & 15))) * 8];
          s[ct] = __builtin_amdgcn_mfma_f32_32x32x16_bf16(kf, qf[d0], s[ct], 0, 0, 0);
        }
      __builtin_amdgcn_s_setprio(0);

      if (kt >= 2 * qt) {  // diagonal tiles only
#pragma unroll
        for (int ct = 0; ct < 2; ct++)
#pragma unroll
          for (int reg = 0; reg < 16; reg++) {
            int ki = kbase + ct * 32 + (reg & 3) + 8 * (reg >> 2) + 4 * hi;
            if (ki > q) s[ct][reg] = -3.0e38f;
          }
      }

      // online softmax (base-2 domain), lane-local row + 1 shfl per quantity
      float tm[16];
#pragma unroll
      for (int i = 0; i < 16; i++) tm[i] = fmaxf(s[0][i], s[1][i]);
#pragma unroll
      for (int st = 8; st > 0; st >>= 1)
#pragma unroll
        for (int i = 0; i < 8; i++)
          if (i < st) tm[i] = fmaxf(tm[i], tm[i + st]);
      float mx = fmaxf(tm[0], __shfl_xor(tm[0], 32));
      float mnew = fmaxf(mrow, mx);
      float al = exp2f(mrow - mnew);
      mrow = mnew;
#pragma unroll
      for (int ct = 0; ct < 2; ct++)
#pragma unroll
        for (int reg = 0; reg < 16; reg++) s[ct][reg] = exp2f(s[ct][reg] - mnew);
      float ts[16];
#pragma unroll
      for (int i = 0; i < 16; i++) ts[i] = s[0][i] + s[1][i];
#pragma unroll
      for (int st = 8; st > 0; st >>= 1)
#pragma unroll
        for (int i = 0; i < 8; i++)
          if (i < st) ts[i] = ts[i] + ts[i + st];
      float rs = ts[0] + __shfl_xor(ts[0], 32);
      lsum = lsum * al + rs;

      // rescale O^T (lane-local: all regs share this lane's q)
#pragma unroll
      for (int db = 0; db < 4; db++)
#pragma unroll
        for (int reg = 0; reg < 16; reg++) oacc[db][reg] *= al;

      // P^T B-fragments via pack + lane-pair exchange (no LDS round trip)
      bf16x8 pb[4];
#pragma unroll
      for (int ks = 0; ks < 4; ks++) {
        const int ct = ks >> 1, s1 = ks & 1;
        unsigned A0 = pk2(s[ct][(2 * s1) * 4 + 0], s[ct][(2 * s1) * 4 + 1]);
        unsigned A1 = pk2(s[ct][(2 * s1) * 4 + 2], s[ct][(2 * s1) * 4 + 3]);
        unsigned B0 = pk2(s[ct][(2 * s1 + 1) * 4 + 0], s[ct][(2 * s1 + 1) * 4 + 1]);
        unsigned B1 = pk2(s[ct][(2 * s1 + 1) * 4 + 2], s[ct][(2 * s1 + 1) * 4 + 3]);
        unsigned z0 = hi ? A0 : B0, z1 = hi ? A1 : B1;   // what partner needs
        unsigned x0 = __shfl_xor(z0, 32), x1 = __shfl_xor(z1, 32);
        union { unsigned u[4]; bf16x8 v; } pw;
        pw.u[0] = hi ? x0 : A0;
        pw.u[1] = hi ? x1 : A1;
        pw.u[2] = hi ? B0 : x0;
        pw.u[3] = hi ? B1 : x1;
        pb[ks] = pw.v;
      }

      // O^T += V^T P^T  (A = V^T: row = d = db*32+l31, k = hi*8+j)
      __builtin_amdgcn_s_setprio(1);
#pragma unroll
      for (int ks = 0; ks < 4; ks++)
#pragma unroll
        for (int db = 0; db < 4; db++) {
          int vr = db * 32 + l31;
          bf16x8 vf = *(const bf16x8*)&Vts[cur][(vr * 8 +
                                                 ((ks * 2 + hi) ^ (vr & 7))) * 8];
          oacc[db] = __builtin_amdgcn_mfma_f32_32x32x16_bf16(vf, pb[ks], oacc[db], 0, 0, 0);
        }
      __builtin_amdgcn_s_setprio(0);

      asm volatile("s_waitcnt vmcnt(0)" ::: "memory");
      __builtin_amdgcn_s_barrier();
    }

    // epilogue: normalize, transpose-free store (4 consecutive d per reg-quad)
    float inv = 1.0f / lsum;
#pragma unroll
    for (int db = 0; db < 4; db++)
#pragma unroll
      for (int q4 = 0; q4 < 4; q4++) {
        bf16x4 o4;
#pragma unroll
        for (int j = 0; j < 4; j++) o4[j] = (bf16)(oacc[db][q4 * 4 + j] * inv);
        int d0 = db * 32 + q4 * 8 + hi * 4;
        *(bf16x4*)&ao[(size_t)(b * 2048 + q) * 4096 + h * 128 + d0] = o4;
      }
  }
#undef STAGE_KV
}

extern "C" void kernel_launch(void* const* d_in, const int* in_sizes, int n_in,
                              void* d_out, int out_size, void* d_ws, size_t ws_size,
                              hipStream_t stream) {
  const float* x = (const float*)d_in[0];
  const float* wq = (const float*)d_in[1];
  const float* wk = (const float*)d_in[2];
  const float* wv = (const float*)d_in[3];
  const float* wo = (const float*)d_in[4];
  float* out = (float*)d_out;

  char* ws = (char*)d_ws;
  bf16* xb = (bf16*)(ws + 0);
  bf16* wt = (bf16*)(ws + 33554432);       // [6144][4096]: wq^T | wk^T | wv^T
  bf16* wot = (bf16*)(ws + 83886080);      // [4096][4096]
  bf16* qkv = (bf16*)(ws + 117440512);     // [4096][6144]
  bf16* vt = (bf16*)(ws + 167772160);      // [16][128][2048]
  bf16* ao = (bf16*)(ws + 176160768);      // [4096][4096]
  if (ws_size < 209715200u) return;        // need ~210MB scratch

  // 1/sqrt(128) * log2(e): softmax runs natively in exp2 domain
  const float qscale = 0.08838834764831845f * 1.4426950408889634f;

  cast_f32_bf16<<<8192, 256, 0, stream>>>(x, xb, 16777216);
  transpose_cast_all<<<dim3(320, 128), dim3(32, 8), 0, stream>>>(
      wq, wk, wv, wo, wt, wot, qscale);

  gemm_bt8<bf16><<<dim3(24, 16), 512, 0, stream>>>(xb, wt, qkv, 4096, 6144, 4096);
  transpose_v<<<dim3(64, 4, 16), dim3(32, 8), 0, stream>>>(qkv, vt);
  flash_attn<<<dim3(8, 32, 2), 256, 0, stream>>>(qkv, vt, ao);
  gemm_bt8<float><<<dim3(16, 16), 512, 0, stream>>>(ao, wot, out, 4096, 4096, 4096);
}

// Round 11
// 650.083 us; speedup vs baseline: 1.2157x; 1.0272x over previous
//
#include <hip/hip_runtime.h>
#include <cstdint>

// SelfAttention fused pipeline, bf16 MFMA path.
// B=2 S=2048 DIM=4096 HQ=32 HKV=8 D=128, causal, start_pos=0.
//
// R13 changes (3rd timeout on R10 stack; gemm_bt8<OT,NBU> held byte-identical,
// audited 3x — plus ONE independent checklist fix in a non-pending kernel):
//  - transpose_cast_all rewritten: 64x64 tiles, float4 loads (16B/lane),
//    bf16x4 stores (8B/lane, 128B segments) — was scalar 4B loads / 2B
//    stores (G13 violation, 2-2.5x measured cost). Semantics verified
//    element-identical; LDS bank pattern 2-way (free).
//  - gemm_bt8<OT,NBU>: qkv 256x192 grid 32x16=512 blocks = exactly 2 full
//    rounds (tail eliminated); out-proj 256x256 grid 256 = 1 round.
//  - flash_attn (R8 swapped-QK^T 32x32) and other kernels frozen.
//
// ws layout (bytes):
//   xb    @ 0         : bf16[4096][4096]   x cast               (33.5 MB)
//   wt    @ 33554432  : bf16[6144][4096]   [wq^T*scale; wk^T; wv^T] (50.3 MB)
//   wot   @ 83886080  : bf16[4096][4096]   wo^T                 (33.5 MB)
//   qkv   @ 117440512 : bf16[4096][6144]   x@[wq wk wv]         (50.3 MB)
//   vt    @ 167772160 : bf16[2][8][128][2048] V^T per kv head   (8.4 MB)
//   ao    @ 176160768 : bf16[4096][4096]   attention output     (33.5 MB)
// total 209715200 bytes.

typedef __bf16 bf16;
typedef __bf16 bf16x4 __attribute__((ext_vector_type(4)));
typedef __bf16 bf16x8 __attribute__((ext_vector_type(8)));
typedef float f32x4 __attribute__((ext_vector_type(4)));
typedef float f32x16 __attribute__((ext_vector_type(16)));

#define DEV_INLINE __device__ __forceinline__

DEV_INLINE void load_lds16(const bf16* g, bf16* l) {
  // async global->LDS, 16B per lane; LDS dest = wave-uniform base + lane*16
  __builtin_amdgcn_global_load_lds(
      (const __attribute__((address_space(1))) void*)g,
      (__attribute__((address_space(3))) void*)l, 16, 0, 0);
}

DEV_INLINE unsigned pk2(float a, float b) {  // two f32 -> packed bf16 pair
  union { bf16 v[2]; unsigned u; } t;
  t.v[0] = (bf16)a; t.v[1] = (bf16)b;
  return t.u;
}

// ---------------- elementwise cast f32 -> bf16, 8 elems/thread ----------------
__global__ __launch_bounds__(256) void cast_f32_bf16(const float* __restrict__ in,
                                                     bf16* __restrict__ out, int n) {
  int i = (blockIdx.x * 256 + threadIdx.x) * 8;
  if (i >= n) return;
  float4 a = *(const float4*)(in + i);
  float4 b = *(const float4*)(in + i + 4);
  bf16x8 o;
  o[0] = (bf16)a.x; o[1] = (bf16)a.y; o[2] = (bf16)a.z; o[3] = (bf16)a.w;
  o[4] = (bf16)b.x; o[5] = (bf16)b.y; o[6] = (bf16)b.z; o[7] = (bf16)b.w;
  *(bf16x8*)(out + i) = o;
}

// --- merged transpose+cast of all 4 weights: f32 [K=4096][N] -> bf16 [N][4096]
// 64x64 tiles, 256 flat threads. Loads float4 (16B/lane), stores bf16x4
// (8B/lane, 128B per 16-lane segment). dst[nrow0+a][k0+b] =
// src[(k0+b)*N + ncol0+a] * scale  (same mapping as the old 32x32 version).
// x-blocks: 0..63 wq (scale) | 64..79 wk | 80..95 wv | 96..159 wo.
__global__ __launch_bounds__(256) void transpose_cast_all(
    const float* __restrict__ wq, const float* __restrict__ wk,
    const float* __restrict__ wv, const float* __restrict__ wo,
    bf16* __restrict__ wt, bf16* __restrict__ wot, float qscale) {
  __shared__ float sm[64][65];
  const int bx = blockIdx.x, k0 = blockIdx.y * 64;
  const float* src;
  bf16* dst;
  int N, ncol0, nrow0;
  float scale = 1.0f;
  if (bx < 64) {         // wq -> wt rows [0,4096)
    src = wq; dst = wt; N = 4096; ncol0 = bx * 64; nrow0 = ncol0; scale = qscale;
  } else if (bx < 80) {  // wk -> wt rows [4096,5120)
    src = wk; dst = wt; N = 1024; ncol0 = (bx - 64) * 64; nrow0 = 4096 + ncol0;
  } else if (bx < 96) {  // wv -> wt rows [5120,6144)
    src = wv; dst = wt; N = 1024; ncol0 = (bx - 80) * 64; nrow0 = 5120 + ncol0;
  } else {               // wo -> wot
    src = wo; dst = wot; N = 4096; ncol0 = (bx - 96) * 64; nrow0 = ncol0;
  }
  const int t = threadIdx.x;
  const int r16 = t >> 4, c4 = (t & 15) * 4;
#pragma unroll
  for (int i = 0; i < 4; i++) {
    int row = r16 + i * 16;
    float4 v = *(const float4*)&src[(size_t)(k0 + row) * N + ncol0 + c4];
    sm[row][c4 + 0] = v.x; sm[row][c4 + 1] = v.y;
    sm[row][c4 + 2] = v.z; sm[row][c4 + 3] = v.w;
  }
  __syncthreads();
#pragma unroll
  for (int i = 0; i < 4; i++) {
    int nr = r16 + i * 16;          // dst row (src col)
    bf16x4 o;
#pragma unroll
    for (int j = 0; j < 4; j++) o[j] = (bf16)(sm[c4 + j][nr] * scale);
    *(bf16x4*)&dst[(size_t)(nrow0 + nr) * 4096 + k0 + c4] = o;
  }
}

// ------ transpose V slice of qkv[4096][6144] -> vt[(b*8+h)*128 + d][2048] -----
__global__ __launch_bounds__(256) void transpose_v(const bf16* __restrict__ qkv,
                                                   bf16* __restrict__ vt) {
  __shared__ bf16 t[32][33];
  int s0 = blockIdx.x * 32, d0 = blockIdx.y * 32, bh = blockIdx.z;
  int b = bh >> 3, h = bh & 7;
  int tx = threadIdx.x, ty = threadIdx.y;
#pragma unroll
  for (int i = 0; i < 32; i += 8)
    t[ty + i][tx] =
        qkv[(size_t)(b * 2048 + s0 + ty + i) * 6144 + 5120 + h * 128 + d0 + tx];
  __syncthreads();
#pragma unroll
  for (int i = 0; i < 32; i += 8)
    vt[((size_t)bh * 128 + d0 + ty + i) * 2048 + s0 + tx] = t[tx][ty + i];
}

// ---------- 2-barrier 256xBN GEMM: C[M][N] = A[M][K] * Bt[N][K]^T ------------
// BN = NBU*64 (192 or 256). 512 threads, waves (rm=w>>2 in 2, cn=w&3 in 4);
// per-wave C = 128 x (BN/4), ni = 0..NBU-1 fragments of 16.
// LDS: 2 dbuf x (4+NBU) units x [64 rows][64 K] bf16 (8 KB/unit),
// XOR-swizzled chunk' = chunk ^ (idx&7). Units 0..3 = A rows
// (unit = (row>>6): rm*2+(mi>>2)); units 4.. = B cols (unit-4 = col>>6).
// Per tile: top { vmcnt(2+NBU)|0 ; barrier ; read aF<-A-h0, bLo ;
//                 stage {1,3}(T+1) }
//   p0 MFMA aF x bLo ; read bHi
//   MID barrier (sched-pinned) ; stage {0,2}(T+2)
//   p1 MFMA aF x bHi ; read aF<-A-h1 ; stage B-units(T+2) split before p2/p3
//   p2 MFMA aF x bLo ; p3 MFMA aF x bHi
// Races: units {0,2,4..} read before MID, staged post-MID (T+2);
// units {1,3} read post-MID, staged after T+1's top barrier. Ledger:
// outstanding at top = {0,2,B}(T) + {1,3}(T) + {0,2,B}(T+1) = 6+2*NBU;
// retire tile T's 4+NBU -> vmcnt(2+NBU). Verified T=0/steady/NT-2/NT-1.
template <typename OT, int NBU>
__global__ __launch_bounds__(512, 2) void gemm_bt8(const bf16* __restrict__ A,
                                                   const bf16* __restrict__ Bt,
                                                   OT* __restrict__ C,
                                                   int M, int N, int K) {
  constexpr int NU = 4 + NBU;
  __shared__ __align__(16) bf16 lds[2][NU][64 * 64];
  const int t = threadIdx.x, w = t >> 6, l = t & 63;
  const int lr = l & 15, lh = l >> 4;
  const int rm = w >> 2, cn = w & 3;
  const int mBase = blockIdx.y * 256, nBase = blockIdx.x * (NBU * 64);
  const int NT = K >> 6;

  // per-thread DMA source: unit-relative row idx + swizzled K-chunk
  const int idx = t >> 3;                  // row within 64-row unit
  const int kc = (t & 7) ^ (idx & 7);      // logical K-chunk stored here
  const size_t u64K = (size_t)64 * K;
  const size_t gA = (size_t)(mBase + idx) * K + kc * 8;
  const size_t gB = (size_t)(nBase + idx) * K + kc * 8;

#define STAGE_U(tile_, u_)                                                   \
  do {                                                                       \
    int th_ = (tile_);                                                       \
    if (th_ < NT) {                                                          \
      const bf16* src_ = ((u_) < 4 ? A + gA + (size_t)(u_)*u64K              \
                                   : Bt + gB + (size_t)((u_)-4) * u64K) +    \
                         (size_t)th_ * 64;                                   \
      load_lds16(src_, &lds[th_ & 1][u_][w * 512]);                          \
    }                                                                        \
  } while (0)

  // prologue groups: {0,2,B..}(0), {1,3}(0), {0,2,B..}(1)
  STAGE_U(0, 0); STAGE_U(0, 2);
#pragma unroll
  for (int u = 4; u < NU; u++) STAGE_U(0, u);
  STAGE_U(0, 1); STAGE_U(0, 3);
  STAGE_U(1, 0); STAGE_U(1, 2);
#pragma unroll
  for (int u = 4; u < NU; u++) STAGE_U(1, u);

  constexpr int NLO = 2, NHI = NBU - 2;
  f32x4 acc[8][NBU] = {};
  bf16x8 aF[4][2], bLo[NLO][2], bHi[NHI][2];
  // read-side addressing (idx&7 == lr&7 for all fragment reads)
  const int xo0 = ((lh ^ (lr & 7)) << 3);             // ks=0 swizzled K-off
  const int xo1 = (((4 + lh) ^ (lr & 7)) << 3);       // ks=1
  // B fragment unit/offset per ni (16-col blocks never straddle units)
  int uB[NBU], oB[NBU];
#pragma unroll
  for (int ni = 0; ni < NBU; ni++) {
    int colb = cn * (NBU * 16) + ni * 16;
    uB[ni] = 4 + (colb >> 6);
    oB[ni] = ((colb & 63) + lr) * 64;
  }

  for (int T = 0; T < NT; T++) {
    // ---- tile top: all DMA for tile T landed (cross-wave via barrier)
    if (T < NT - 1) {
      if constexpr (NBU == 3) asm volatile("s_waitcnt vmcnt(5)" ::: "memory");
      else                    asm volatile("s_waitcnt vmcnt(6)" ::: "memory");
    } else {
      asm volatile("s_waitcnt vmcnt(0)" ::: "memory");
    }
    __builtin_amdgcn_s_barrier();
    const int par = T & 1;

    // top reads: A-h0 (unit rm*2) and bLo (compiler inserts lgkmcnt)
#pragma unroll
    for (int mi = 0; mi < 4; mi++) {
      const bf16* qa = &lds[par][rm * 2][(mi * 16 + lr) * 64];
      aF[mi][0] = *(const bf16x8*)(qa + xo0);
      aF[mi][1] = *(const bf16x8*)(qa + xo1);
    }
#pragma unroll
    for (int ni = 0; ni < NLO; ni++) {
      const bf16* qb = &lds[par][uB[ni]][oB[ni]];
      bLo[ni][0] = *(const bf16x8*)(qb + xo0);
      bLo[ni][1] = *(const bf16x8*)(qb + xo1);
    }
    STAGE_U(T + 1, 1); STAGE_U(T + 1, 3);

    // p0: acc[0..3][0..NLO) += aF(A-h0) x bLo
    __builtin_amdgcn_s_setprio(1);
#pragma unroll
    for (int ks = 0; ks < 2; ks++)
#pragma unroll
      for (int mi = 0; mi < 4; mi++)
#pragma unroll
        for (int ni = 0; ni < NLO; ni++)
          acc[mi][ni] = __builtin_amdgcn_mfma_f32_16x16x32_bf16(
              aF[mi][ks], bLo[ni][ks], acc[mi][ni], 0, 0, 0);
    __builtin_amdgcn_s_setprio(0);
    // read bHi (tile T) — must issue before MID barrier
#pragma unroll
    for (int ni = 0; ni < NHI; ni++) {
      const bf16* qb = &lds[par][uB[NLO + ni]][oB[NLO + ni]];
      bHi[ni][0] = *(const bf16x8*)(qb + xo0);
      bHi[ni][1] = *(const bf16x8*)(qb + xo1);
    }

    // ---- MID barrier: separates tile-T reads of units {0,2,4..} from
    // their same-buffer overwriting stages (T+2). sched-pinned both sides.
    __builtin_amdgcn_sched_barrier(0);
    __builtin_amdgcn_s_barrier();
    __builtin_amdgcn_sched_barrier(0);
    STAGE_U(T + 2, 0); STAGE_U(T + 2, 2);

    // p1: acc[0..3][NLO..] += aF(A-h0) x bHi
    __builtin_amdgcn_s_setprio(1);
#pragma unroll
    for (int ks = 0; ks < 2; ks++)
#pragma unroll
      for (int mi = 0; mi < 4; mi++)
#pragma unroll
        for (int ni = 0; ni < NHI; ni++)
          acc[mi][NLO + ni] = __builtin_amdgcn_mfma_f32_16x16x32_bf16(
              aF[mi][ks], bHi[ni][ks], acc[mi][NLO + ni], 0, 0, 0);
    __builtin_amdgcn_s_setprio(0);
    // read A-h1 into aF (WAR reuse; in-order wave). Overwrite A-h1 units
    // {1,3}(T+2) stages after T+1's top barrier.
#pragma unroll
    for (int mi = 0; mi < 4; mi++) {
      const bf16* qa = &lds[par][rm * 2 + 1][(mi * 16 + lr) * 64];
      aF[mi][0] = *(const bf16x8*)(qa + xo0);
      aF[mi][1] = *(const bf16x8*)(qa + xo1);
    }
    STAGE_U(T + 2, 4); STAGE_U(T + 2, 5);

    // p2: acc[4..7][0..NLO) += aF(A-h1) x bLo
    __builtin_amdgcn_s_setprio(1);
#pragma unroll
    for (int ks = 0; ks < 2; ks++)
#pragma unroll
      for (int mi = 0; mi < 4; mi++)
#pragma unroll
        for (int ni = 0; ni < NLO; ni++)
          acc[4 + mi][ni] = __builtin_amdgcn_mfma_f32_16x16x32_bf16(
              aF[mi][ks], bLo[ni][ks], acc[4 + mi][ni], 0, 0, 0);
    __builtin_amdgcn_s_setprio(0);
#pragma unroll
    for (int u = 6; u < NU; u++) STAGE_U(T + 2, u);

    // p3: acc[4..7][NLO..] += aF(A-h1) x bHi
    __builtin_amdgcn_s_setprio(1);
#pragma unroll
    for (int ks = 0; ks < 2; ks++)
#pragma unroll
      for (int mi = 0; mi < 4; mi++)
#pragma unroll
        for (int ni = 0; ni < NHI; ni++)
          acc[4 + mi][NLO + ni] = __builtin_amdgcn_mfma_f32_16x16x32_bf16(
              aF[mi][ks], bHi[ni][ks], acc[4 + mi][NLO + ni], 0, 0, 0);
    __builtin_amdgcn_s_setprio(0);
  }
#undef STAGE_U

  // epilogue (C/D layout: col=lr, row=lh*4+r within fragment)
#pragma unroll
  for (int mi = 0; mi < 8; mi++)
#pragma unroll
    for (int ni = 0; ni < NBU; ni++) {
      int row = mBase + rm * 128 + mi * 16 + lh * 4;
      int col = nBase + cn * (NBU * 16) + ni * 16 + lr;
#pragma unroll
      for (int r = 0; r < 4; r++)
        C[(size_t)(row + r) * N + col] = (OT)acc[mi][ni][r];
    }
}

// ------------------------------ flash attention ------------------------------
// (frozen from R8 — swapped-QK^T 32x32, in-register softmax, K/V dbuf, 64 KB)
__global__ __launch_bounds__(256, 2) void flash_attn(const bf16* __restrict__ qkv,
                                                     const bf16* __restrict__ vt,
                                                     bf16* __restrict__ ao) {
  __shared__ __align__(16) bf16 Ks[2][64 * 128];
  __shared__ __align__(16) bf16 Vts[2][128 * 64];
  const int t = threadIdx.x, w = t >> 6, l = t & 63;
  const int l31 = l & 31, hi = l >> 5;
  const int h = blockIdx.y, b = blockIdx.z;
  const int hkv = h >> 2;

#define STAGE_KV(kt_, buf_)                                                   \
  do {                                                                        \
    const int kb_ = (kt_) * 64;                                               \
    _Pragma("unroll")                                                         \
    for (int p = 0; p < 4; p++) {                                             \
      int c = p * 256 + t;                                                    \
      int ldsoff = (p * 256 + w * 64) * 8;                                    \
      int krow = c >> 4, kj = (c & 15) ^ (krow & 15);                         \
      load_lds16(qkv + (size_t)(b * 2048 + kb_ + krow) * 6144 + 4096 +        \
                     hkv * 128 + kj * 8,                                      \
                 &Ks[buf_][ldsoff]);                                          \
      int vrow = c >> 3, vj = (c & 7) ^ (vrow & 7);                           \
      load_lds16(vt + ((size_t)(b * 8 + hkv) * 128 + vrow) * 2048 + kb_ +     \
                     vj * 8,                                                  \
                 &Vts[buf_][ldsoff]);                                         \
    }                                                                         \
  } while (0)

  for (int phase = 0; phase < 2; phase++) {
    const int qt = phase == 0 ? blockIdx.x : 15 - blockIdx.x;
    const int qrow0 = qt * 128 + w * 32;
    const int nkt = 2 * qt + 2;
    const int q = qrow0 + l31;  // this lane's q row (shared with lane l^32)

    STAGE_KV(0, 0);

    // Q as B-operand: col = q = l31, contraction-d = d0*16 + hi*8 + j
    bf16x8 qf[8];
#pragma unroll
    for (int d0 = 0; d0 < 8; d0++)
      qf[d0] = *(const bf16x8*)&qkv[(size_t)(b * 2048 + q) * 6144 + h * 128 +
                                    d0 * 16 + hi * 8];

    f32x16 oacc[4] = {};  // O^T: oacc[db][reg], d = db*32+(reg&3)+8*(reg>>2)+4*hi
    float mrow = -3.0e38f, lsum = 0.f;

    asm volatile("s_waitcnt vmcnt(0)" ::: "memory");
    __builtin_amdgcn_s_barrier();

    for (int kt = 0; kt < nkt; kt++) {
      const int cur = kt & 1;
      const int kbase = kt * 64;
      if (kt + 1 < nkt) STAGE_KV(kt + 1, cur ^ 1);

      // S^T = K Q^T: s[ct][reg], k = kbase+ct*32+(reg&3)+8*(reg>>2)+4*hi
      f32x16 s[2] = {};
      __builtin_amdgcn_s_setprio(1);
#pragma unroll
      for (int d0 = 0; d0 < 8; d0++)
#pragma unroll
        for (int ct = 0; ct < 2; ct++) {
          int krow = ct * 32 + l31;
          bf16x8 kf = *(const bf16x8*)&Ks[cur][(krow * 16 +
                                                ((d0 * 2 + hi) ^ (krow & 15))) * 8];
          s[ct] = __builtin_amdgcn_mfma_f32_32x32x16_bf16(kf, qf[d0], s[ct], 0, 0, 0);
        }
      __builtin_amdgcn_s_setprio(0);

      if (kt >= 2 * qt) {  // diagonal tiles only
#pragma unroll
        for (int ct = 0; ct < 2; ct++)
#pragma unroll
          for (int reg = 0; reg < 16; reg++) {
            int ki = kbase + ct * 32 + (reg & 3) + 8 * (reg >> 2) + 4 * hi;
            if (ki > q) s[ct][reg] = -3.0e38f;
          }
      }

      // online softmax (base-2 domain), lane-local row + 1 shfl per quantity
      float tm[16];
#pragma unroll
      for (int i = 0; i < 16; i++) tm[i] = fmaxf(s[0][i], s[1][i]);
#pragma unroll
      for (int st = 8; st > 0; st >>= 1)
#pragma unroll
        for (int i = 0; i < 8; i++)
          if (i < st) tm[i] = fmaxf(tm[i], tm[i + st]);
      float mx = fmaxf(tm[0], __shfl_xor(tm[0], 32));
      float mnew = fmaxf(mrow, mx);
      float al = exp2f(mrow - mnew);
      mrow = mnew;
#pragma unroll
      for (int ct = 0; ct < 2; ct++)
#pragma unroll
        for (int reg = 0; reg < 16; reg++) s[ct][reg] = exp2f(s[ct][reg] - mnew);
      float ts[16];
#pragma unroll
      for (int i = 0; i < 16; i++) ts[i] = s[0][i] + s[1][i];
#pragma unroll
      for (int st = 8; st > 0; st >>= 1)
#pragma unroll
        for (int i = 0; i < 8; i++)
          if (i < st) ts[i] = ts[i] + ts[i + st];
      float rs = ts[0] + __shfl_xor(ts[0], 32);
      lsum = lsum * al + rs;

      // rescale O^T (lane-local: all regs share this lane's q)
#pragma unroll
      for (int db = 0; db < 4; db++)
#pragma unroll
        for (int reg = 0; reg < 16; reg++) oacc[db][reg] *= al;

      // P^T B-fragments via pack + lane-pair exchange (no LDS round trip)
      bf16x8 pb[4];
#pragma unroll
      for (int ks = 0; ks < 4; ks++) {
        const int ct = ks >> 1, s1 = ks & 1;
        unsigned A0 = pk2(s[ct][(2 * s1) * 4 + 0], s[ct][(2 * s1) * 4 + 1]);
        unsigned A1 = pk2(s[ct][(2 * s1) * 4 + 2], s[ct][(2 * s1) * 4 + 3]);
        unsigned B0 = pk2(s[ct][(2 * s1 + 1) * 4 + 0], s[ct][(2 * s1 + 1) * 4 + 1]);
        unsigned B1 = pk2(s[ct][(2 * s1 + 1) * 4 + 2], s[ct][(2 * s1 + 1) * 4 + 3]);
        unsigned z0 = hi ? A0 : B0, z1 = hi ? A1 : B1;   // what partner needs
        unsigned x0 = __shfl_xor(z0, 32), x1 = __shfl_xor(z1, 32);
        union { unsigned u[4]; bf16x8 v; } pw;
        pw.u[0] = hi ? x0 : A0;
        pw.u[1] = hi ? x1 : A1;
        pw.u[2] = hi ? B0 : x0;
        pw.u[3] = hi ? B1 : x1;
        pb[ks] = pw.v;
      }

      // O^T += V^T P^T  (A = V^T: row = d = db*32+l31, k = hi*8+j)
      __builtin_amdgcn_s_setprio(1);
#pragma unroll
      for (int ks = 0; ks < 4; ks++)
#pragma unroll
        for (int db = 0; db < 4; db++) {
          int vr = db * 32 + l31;
          bf16x8 vf = *(const bf16x8*)&Vts[cur][(vr * 8 +
                                                 ((ks * 2 + hi) ^ (vr & 7))) * 8];
          oacc[db] = __builtin_amdgcn_mfma_f32_32x32x16_bf16(vf, pb[ks], oacc[db], 0, 0, 0);
        }
      __builtin_amdgcn_s_setprio(0);

      asm volatile("s_waitcnt vmcnt(0)" ::: "memory");
      __builtin_amdgcn_s_barrier();
    }

    // epilogue: normalize, transpose-free store (4 consecutive d per reg-quad)
    float inv = 1.0f / lsum;
#pragma unroll
    for (int db = 0; db < 4; db++)
#pragma unroll
      for (int q4 = 0; q4 < 4; q4++) {
        bf16x4 o4;
#pragma unroll
        for (int j = 0; j < 4; j++) o4[j] = (bf16)(oacc[db][q4 * 4 + j] * inv);
        int d0 = db * 32 + q4 * 8 + hi * 4;
        *(bf16x4*)&ao[(size_t)(b * 2048 + q) * 4096 + h * 128 + d0] = o4;
      }
  }
#undef STAGE_KV
}

extern "C" void kernel_launch(void* const* d_in, const int* in_sizes, int n_in,
                              void* d_out, int out_size, void* d_ws, size_t ws_size,
                              hipStream_t stream) {
  const float* x = (const float*)d_in[0];
  const float* wq = (const float*)d_in[1];
  const float* wk = (const float*)d_in[2];
  const float* wv = (const float*)d_in[3];
  const float* wo = (const float*)d_in[4];
  float* out = (float*)d_out;

  char* ws = (char*)d_ws;
  bf16* xb = (bf16*)(ws + 0);
  bf16* wt = (bf16*)(ws + 33554432);       // [6144][4096]: wq^T | wk^T | wv^T
  bf16* wot = (bf16*)(ws + 83886080);      // [4096][4096]
  bf16* qkv = (bf16*)(ws + 117440512);     // [4096][6144]
  bf16* vt = (bf16*)(ws + 167772160);      // [16][128][2048]
  bf16* ao = (bf16*)(ws + 176160768);      // [4096][4096]
  if (ws_size < 209715200u) return;        // need ~210MB scratch

  // 1/sqrt(128) * log2(e): softmax runs natively in exp2 domain
  const float qscale = 0.08838834764831845f * 1.4426950408889634f;

  cast_f32_bf16<<<8192, 256, 0, stream>>>(x, xb, 16777216);
  transpose_cast_all<<<dim3(160, 64), 256, 0, stream>>>(
      wq, wk, wv, wo, wt, wot, qscale);

  gemm_bt8<bf16, 3><<<dim3(32, 16), 512, 0, stream>>>(xb, wt, qkv, 4096, 6144, 4096);
  transpose_v<<<dim3(64, 4, 16), dim3(32, 8), 0, stream>>>(qkv, vt);
  flash_attn<<<dim3(8, 32, 2), 256, 0, stream>>>(qkv, vt, ao);
  gemm_bt8<float, 4><<<dim3(16, 16), 512, 0, stream>>>(ao, wot, out, 4096, 4096, 4096);
}